// Round 7
// baseline (2302.173 us; speedup 1.0000x reference)
//
#include <hip/hip_runtime.h>
#include <hip/hip_bf16.h>

#define N_NODES 100000
#define N_EDGES 1600000
#define DIM 128
#define NLAY 3
#define NRES 3
#define NCODE 16
#define NGRAPH 512
#define SCAN_NB ((N_NODES + 255) / 256)  // 391
#define GEMM_NB ((N_NODES + 63) / 64)    // 1563

using bf16 = __hip_bfloat16;

__device__ inline void atomAddD(double* p, double v) { unsafeAtomicAdd(p, v); }

// flag==1: external float-typed arrays are bf16; flag==0: they are fp32.
__device__ inline double ldx(const void* p, long i, int isbf) {
  if (isbf) return (double)__bfloat162float(((const bf16*)p)[i]);
  return (double)((const float*)p)[i];
}
__device__ inline void stout(void* p, long i, double v, int isbf) {
  if (isbf) ((bf16*)p)[i] = __float2bfloat16((float)v);
  else ((float*)p)[i] = (float)v;
}

// ---------- dtype detection: bf16 vs fp32 bit-pattern statistics ----------
__global__ void k_detect(const unsigned int* __restrict__ x, int* __restrict__ flag) {
  int tid = threadIdx.x;  // 256
  int cnt = 0;
  for (int j = tid; j < 1024; j += 256) {
    unsigned int u = x[j];
    int e = (u >> 7) & 0xFF;  // exponent field of the LOW u16 viewed as bf16
    cnt += (e >= 100 && e <= 135) ? 1 : 0;
  }
  __shared__ int sh[256];
  sh[tid] = cnt; __syncthreads();
  for (int s = 128; s; s >>= 1) { if (tid < s) sh[tid] += sh[tid + s]; __syncthreads(); }
  if (tid == 0) flag[0] = (sh[0] > 512) ? 1 : 0;
}

// ---------- external -> fp32 convert ----------
__global__ __launch_bounds__(256) void k_convert_f(const void* __restrict__ x, float* __restrict__ hf,
                                                   long n, const int* __restrict__ flag) {
  int isbf = flag[0];
  long i = (long)blockIdx.x * 256 + threadIdx.x;
  if (i < n) hf[i] = (float)ldx(x, i, isbf);
}

// ---------- CSR build: histogram ----------
__global__ __launch_bounds__(256) void k_hist(const int* __restrict__ ei, int* __restrict__ deg) {
  int e = blockIdx.x * 256 + threadIdx.x;
  if (e < N_EDGES) atomicAdd(&deg[ei[N_EDGES + e]], 1);
}

// ---------- CSR build: hierarchical exclusive scan (3 phases, all parallel) ----------
__global__ __launch_bounds__(256) void k_scan1(const int* __restrict__ deg, int* __restrict__ bsum) {
  int i = blockIdx.x * 256 + threadIdx.x;
  int v = (i < N_NODES) ? deg[i] : 0;
  for (int o = 32; o; o >>= 1) v += __shfl_xor(v, o);
  __shared__ int sh[4];
  if ((threadIdx.x & 63) == 0) sh[threadIdx.x >> 6] = v;
  __syncthreads();
  if (threadIdx.x == 0) bsum[blockIdx.x] = sh[0] + sh[1] + sh[2] + sh[3];
}

__global__ void k_scan2(int* __restrict__ bsum) {
  __shared__ int sh[512];
  int t = threadIdx.x;
  int v = (t < SCAN_NB) ? bsum[t] : 0;
  sh[t] = v; __syncthreads();
  for (int s = 1; s < 512; s <<= 1) {
    int add = (t >= s) ? sh[t - s] : 0;
    __syncthreads();
    sh[t] += add;
    __syncthreads();
  }
  if (t < SCAN_NB) bsum[t] = sh[t] - v;  // exclusive
}

__global__ __launch_bounds__(256) void k_scan3(const int* __restrict__ deg, const int* __restrict__ bsum,
                                               int* __restrict__ ofs, int* __restrict__ cursor) {
  int t = threadIdx.x;
  int i = blockIdx.x * 256 + t;
  int v = (i < N_NODES) ? deg[i] : 0;
  __shared__ int sh[256];
  sh[t] = v; __syncthreads();
  for (int s = 1; s < 256; s <<= 1) {
    int add = (t >= s) ? sh[t - s] : 0;
    __syncthreads();
    sh[t] += add;
    __syncthreads();
  }
  int excl = sh[t] - v + bsum[blockIdx.x];
  if (i < N_NODES) { ofs[i] = excl; cursor[i] = excl; }
  if (i == N_NODES - 1) ofs[N_NODES] = excl + v;
}

// ---------- CSR build: fill ----------
__global__ __launch_bounds__(256) void k_fill(const int* __restrict__ ei, int* __restrict__ cursor,
                                              int* __restrict__ csr) {
  int e = blockIdx.x * 256 + threadIdx.x;
  if (e < N_EDGES) {
    int d = ei[N_EDGES + e];
    int p = atomicAdd(&cursor[d], 1);
    csr[p] = ei[e];
  }
}

// ---------- normalize codebooks (fp64) ----------
__global__ void k_cbn(const void* __restrict__ cb, double* __restrict__ cbn, const int* __restrict__ flag) {
  int isbf = flag[0];
  int b = blockIdx.x, d = threadIdx.x;  // 144 blocks x 64 threads
  double v0 = ldx(cb, (long)b * DIM + d, isbf);
  double v1 = ldx(cb, (long)b * DIM + d + 64, isbf);
  double ss = v0 * v0 + v1 * v1;
  for (int o = 32; o; o >>= 1) ss += __shfl_xor(ss, o);
  double inv = 1.0 / sqrt(ss + 1e-12);
  cbn[b * DIM + d] = v0 * inv;
  cbn[b * DIM + d + 64] = v1 * inv;
}

// ---------- Gram matrices per layer ----------
__global__ void k_gram(const double* __restrict__ cbn, double* __restrict__ G) {
  int b = blockIdx.x, t = threadIdx.x;  // 3*48*48 blocks x 64
  int l = b / (48 * 48); int rem = b % (48 * 48); int a = rem / 48, c = rem % 48;
  const double* ra = cbn + (long)(l * 48 + a) * DIM;
  const double* rc = cbn + (long)(l * 48 + c) * DIM;
  double s = ra[t] * rc[t] + ra[t + 64] * rc[t + 64];
  for (int o = 32; o; o >>= 1) s += __shfl_xor(s, o);
  if (t == 0) G[b] = s;
}

// ---------- FUSED gather + GEMM1 + bias + relu ----------
// Gather phase: fp64 accumulation in csr-index order (bit-identical to k_gather:
// sequential adds in index order; unroll width only affects load scheduling).
// GEMM phase: VERBATIM Round-3 inner loop reading the gathered tile from LDS.
__global__ __launch_bounds__(256) void k_gathgemm1(const float* __restrict__ hf,
                                                   const int* __restrict__ ofs,
                                                   const int* __restrict__ csr,
                                                   const float* __restrict__ W,
                                                   const float* __restrict__ bias,
                                                   float* __restrict__ out) {
  __shared__ float ul[64 * DIM];  // 32 KB
  int tid = threadIdx.x;
  long base = (long)blockIdx.x * 64;
  int wave = tid >> 6, lane = tid & 63;
  // gather phase: each wave produces 16 rows of the tile
  for (int i = 0; i < 16; i++) {
    int row = wave * 16 + i;
    long node = base + row;
    double accx = 0.0, accy = 0.0;
    if (node < N_NODES) {
      int beg = ofs[node], end = ofs[node + 1];
      float2 sv = *(const float2*)&hf[node * DIM + lane * 2];
      accx = (double)sv.x; accy = (double)sv.y;
      int j = beg;
      for (; j + 7 < end; j += 8) {
        int s0 = csr[j], s1 = csr[j + 1], s2 = csr[j + 2], s3 = csr[j + 3];
        int s4 = csr[j + 4], s5 = csr[j + 5], s6 = csr[j + 6], s7 = csr[j + 7];
        float2 v0 = *(const float2*)&hf[(long)s0 * DIM + lane * 2];
        float2 v1 = *(const float2*)&hf[(long)s1 * DIM + lane * 2];
        float2 v2 = *(const float2*)&hf[(long)s2 * DIM + lane * 2];
        float2 v3 = *(const float2*)&hf[(long)s3 * DIM + lane * 2];
        float2 v4 = *(const float2*)&hf[(long)s4 * DIM + lane * 2];
        float2 v5 = *(const float2*)&hf[(long)s5 * DIM + lane * 2];
        float2 v6 = *(const float2*)&hf[(long)s6 * DIM + lane * 2];
        float2 v7 = *(const float2*)&hf[(long)s7 * DIM + lane * 2];
        accx += (double)v0.x; accy += (double)v0.y;
        accx += (double)v1.x; accy += (double)v1.y;
        accx += (double)v2.x; accy += (double)v2.y;
        accx += (double)v3.x; accy += (double)v3.y;
        accx += (double)v4.x; accy += (double)v4.y;
        accx += (double)v5.x; accy += (double)v5.y;
        accx += (double)v6.x; accy += (double)v6.y;
        accx += (double)v7.x; accy += (double)v7.y;
      }
      for (; j < end; j++) {
        int s0 = csr[j];
        float2 v0 = *(const float2*)&hf[(long)s0 * DIM + lane * 2];
        accx += (double)v0.x; accy += (double)v0.y;
      }
    }
    *(float2*)&ul[row * DIM + lane * 2] = make_float2((float)accx, (float)accy);
  }
  __syncthreads();
  // GEMM phase — VERBATIM Round-3 body
  int cl = tid & 31;   // 32 col groups x 4 cols
  int rw = tid >> 5;   // 8 row groups x 8 rows
  int c0 = cl * 4;
  float acc[8][4] = {};
  for (int k = 0; k < DIM; k += 4) {
    float4 w0 = *(const float4*)&W[(k + 0) * DIM + c0];
    float4 w1 = *(const float4*)&W[(k + 1) * DIM + c0];
    float4 w2 = *(const float4*)&W[(k + 2) * DIM + c0];
    float4 w3 = *(const float4*)&W[(k + 3) * DIM + c0];
#pragma unroll
    for (int r = 0; r < 8; r++) {
      float4 u = *(const float4*)&ul[(rw * 8 + r) * DIM + k];
      acc[r][0] += u.x * w0.x + u.y * w1.x + u.z * w2.x + u.w * w3.x;
      acc[r][1] += u.x * w0.y + u.y * w1.y + u.z * w2.y + u.w * w3.y;
      acc[r][2] += u.x * w0.z + u.y * w1.z + u.z * w2.z + u.w * w3.z;
      acc[r][3] += u.x * w0.w + u.y * w1.w + u.z * w2.w + u.w * w3.w;
    }
  }
  float4 bv = *(const float4*)&bias[c0];
#pragma unroll
  for (int r = 0; r < 8; r++) {
    long row = base + rw * 8 + r;
    if (row < N_NODES) {
      float4 o;
      o.x = fmaxf(acc[r][0] + bv.x, 0.f);
      o.y = fmaxf(acc[r][1] + bv.y, 0.f);
      o.z = fmaxf(acc[r][2] + bv.z, 0.f);
      o.w = fmaxf(acc[r][3] + bv.w, 0.f);
      *(float4*)&out[row * DIM + c0] = o;
    }
  }
}

// ---------- fp32 GEMM + bias + relu: VERBATIM Round-3 kernel ----------
__global__ __launch_bounds__(256) void k_gemm_relu_f(const float* __restrict__ in,
                                                     const float* __restrict__ W,
                                                     const float* __restrict__ bias,
                                                     float* __restrict__ out) {
  __shared__ float ul[64 * DIM];  // 32 KB
  int tid = threadIdx.x;
  long base = (long)blockIdx.x * 64;
  for (int j = tid; j < 64 * DIM / 4; j += 256) {
    long row = base + (j >> 5);
    float4 v = make_float4(0.f, 0.f, 0.f, 0.f);
    if (row < N_NODES) v = *(const float4*)&in[base * DIM + (long)j * 4];
    *(float4*)&ul[j * 4] = v;
  }
  __syncthreads();
  int cl = tid & 31;
  int rw = tid >> 5;
  int c0 = cl * 4;
  float acc[8][4] = {};
  for (int k = 0; k < DIM; k += 4) {
    float4 w0 = *(const float4*)&W[(k + 0) * DIM + c0];
    float4 w1 = *(const float4*)&W[(k + 1) * DIM + c0];
    float4 w2 = *(const float4*)&W[(k + 2) * DIM + c0];
    float4 w3 = *(const float4*)&W[(k + 3) * DIM + c0];
#pragma unroll
    for (int r = 0; r < 8; r++) {
      float4 u = *(const float4*)&ul[(rw * 8 + r) * DIM + k];
      acc[r][0] += u.x * w0.x + u.y * w1.x + u.z * w2.x + u.w * w3.x;
      acc[r][1] += u.x * w0.y + u.y * w1.y + u.z * w2.y + u.w * w3.y;
      acc[r][2] += u.x * w0.z + u.y * w1.z + u.z * w2.z + u.w * w3.z;
      acc[r][3] += u.x * w0.w + u.y * w1.w + u.z * w2.w + u.w * w3.w;
    }
  }
  float4 bv = *(const float4*)&bias[c0];
#pragma unroll
  for (int r = 0; r < 8; r++) {
    long row = base + rw * 8 + r;
    if (row < N_NODES) {
      float4 o;
      o.x = fmaxf(acc[r][0] + bv.x, 0.f);
      o.y = fmaxf(acc[r][1] + bv.y, 0.f);
      o.z = fmaxf(acc[r][2] + bv.z, 0.f);
      o.w = fmaxf(acc[r][3] + bv.w, 0.f);
      *(float4*)&out[row * DIM + c0] = o;
    }
  }
}

// ---------- BN stats (fp32 in, fp64 accum) — VERBATIM Round-3 kernel ----------
__global__ __launch_bounds__(256) void k_bn_stats(const float* __restrict__ h, double* __restrict__ stats) {
  int tid = threadIdx.x; int col = tid & 127; int half = tid >> 7;
  double s = 0.0, s2 = 0.0;
  for (long r = blockIdx.x * 2 + half; r < N_NODES; r += 2048) {
    double v = (double)h[r * DIM + col];
    s += v; s2 += v * v;
  }
  __shared__ double ls[256], ls2[256];
  ls[tid] = s; ls2[tid] = s2;
  __syncthreads();
  if (tid < 128) {
    atomAddD(&stats[col], ls[tid] + ls[tid + 128]);
    atomAddD(&stats[DIM + col], ls2[tid] + ls2[tid + 128]);
  }
}

// ---------- fused post v2: bn_prep + normalize + xs + hh + xpool + dotH + VQ ----------
// normalize/hq/xpool: verbatim k_post (verified).  bn_prep formula: verbatim (deterministic,
// identical in every block).  dot expression: verbatim k_dotH with the fp64 codebook read
// from GLOBAL (same values as the old LDS copy).  VQ selection: verbatim k_vq reading the
// (float)-rounded dots from LDS (identical rounding to the old dH store).
__global__ __launch_bounds__(256) void k_post2(float* __restrict__ h,
                                               const double* __restrict__ stats,
                                               const void* __restrict__ gamma,
                                               const void* __restrict__ beta,
                                               const double* __restrict__ cbnL,
                                               const double* __restrict__ Gg,
                                               const int* __restrict__ batch,
                                               void* __restrict__ out,
                                               double* __restrict__ xpool,
                                               double* __restrict__ commit,
                                               int l, const int* __restrict__ flag) {
  __shared__ float hl[64 * 132];   // normalized tile (fp32), padded
  __shared__ float dhl[64 * 49];   // dots fp32, stride 49
  __shared__ double hq[64 * 4];    // ||h||^2 quarter-partials
  __shared__ double ssl[256];      // BN scale/shift
  __shared__ int sbat[64];
  int isbf = flag[0];
  int tid = threadIdx.x;
  long base = (long)blockIdx.x * 64;
  // bn_prep folded (verbatim formula; deterministic)
  if (tid < 128) {
    int dd = tid;
    double mean = stats[dd] / (double)N_NODES;
    double var = stats[DIM + dd] / (double)N_NODES - mean * mean;
    double sc = ldx(gamma, (long)l * DIM + dd, isbf) / sqrt(var + 1e-5);
    ssl[dd] = sc;
    ssl[DIM + dd] = ldx(beta, (long)l * DIM + dd, isbf) - mean * sc;
  }
  if (tid < 64) {
    long row = base + tid;
    sbat[tid] = (row < N_NODES) ? batch[row] : -1;
  }
  __syncthreads();
  // phase 1: normalize (fp64 math) + write h + xs + stage tile  [verbatim k_post]
  int d = tid & 127, half = tid >> 7;
  double sc = ssl[d], sh = ssl[DIM + d];
  const long XS_BASE = (long)NGRAPH * DIM * NLAY;
  for (int rr = half; rr < 64; rr += 2) {
    long row = base + rr;
    float vf = 0.f;
    if (row < N_NODES) {
      double v = (double)h[row * DIM + d] * sc + sh;
      vf = (float)v;
      h[row * DIM + d] = vf;
      stout(out, XS_BASE + row * (DIM * NLAY) + l * DIM + d, v, isbf);
    }
    hl[rr * 132 + d] = vf;
  }
  __syncthreads();
  // phase 2a: dots [verbatim k_dotH expression; codebook from global fp64]
  {
    int ct = tid & 7; int c0 = ct * 6; int rt = tid >> 3;
    double acc0[6] = {}, acc1[6] = {};
    for (int k = 0; k < DIM; k += 4) {
      float4 h0 = *(const float4*)&hl[rt * 132 + k];
      float4 h1 = *(const float4*)&hl[(rt + 32) * 132 + k];
#pragma unroll
      for (int j = 0; j < 6; j++) {
        double2 ca = *(const double2*)&cbnL[(long)(c0 + j) * DIM + k];
        double2 cb = *(const double2*)&cbnL[(long)(c0 + j) * DIM + k + 2];
        acc0[j] += (double)h0.x * ca.x + (double)h0.y * ca.y + (double)h0.z * cb.x + (double)h0.w * cb.y;
        acc1[j] += (double)h1.x * ca.x + (double)h1.y * ca.y + (double)h1.z * cb.x + (double)h1.w * cb.y;
      }
    }
#pragma unroll
    for (int j = 0; j < 6; j++) {
      dhl[rt * 49 + c0 + j] = (float)acc0[j];
      dhl[(rt + 32) * 49 + c0 + j] = (float)acc1[j];
    }
  }
  // phase 2b: hh quarter-partials [verbatim k_post]
  {
    int row = tid >> 2, q = tid & 3;
    double s2 = 0.0;
    const float* hp = &hl[row * 132 + q * 32];
#pragma unroll
    for (int i = 0; i < 32; i++) { double v = (double)hp[i]; s2 += v * v; }
    hq[row * 4 + q] = s2;
  }
  __syncthreads();
  // phase 3 (wave 0): VQ select [verbatim k_vq] ; (waves 2-3): xpool [verbatim k_post]
  if (tid < 64) {
    long n = base + tid;
    double csum = 0.0;
    if (n < N_NODES) {
      double dh[48];
#pragma unroll
      for (int c = 0; c < 48; c++) dh[c] = (double)dhl[tid * 49 + c];
      double hhv = hq[tid * 4] + hq[tid * 4 + 1] + hq[tid * 4 + 2] + hq[tid * 4 + 3];
      int i0 = 0; double b0 = dh[0];
#pragma unroll
      for (int c = 1; c < 16; c++) { if (dh[c] > b0) { b0 = dh[c]; i0 = c; } }
      int i1 = 0; double b1 = dh[16] - Gg[i0 * 48 + 16];
#pragma unroll
      for (int c = 1; c < 16; c++) {
        double s = dh[16 + c] - Gg[i0 * 48 + 16 + c];
        if (s > b1) { b1 = s; i1 = c; }
      }
      int i2 = 0; double b2 = dh[32] - Gg[i0 * 48 + 32] - Gg[(16 + i1) * 48 + 32];
#pragma unroll
      for (int c = 1; c < 16; c++) {
        double s = dh[32 + c] - Gg[i0 * 48 + 32 + c] - Gg[(16 + i1) * 48 + 32 + c];
        if (s > b2) { b2 = s; i2 = c; }
      }
      double r1s = hhv - 2.0 * b0 + Gg[i0 * 48 + i0];
      double r2s = r1s - 2.0 * b1 + Gg[(16 + i1) * 48 + 16 + i1];
      double r3s = r2s - 2.0 * b2 + Gg[(32 + i2) * 48 + 32 + i2];
      csum = r1s + r2s + r3s;
      const long IDS_BASE = (long)NGRAPH * DIM * NLAY + (long)N_NODES * DIM * NLAY + 1;
      long ib = IDS_BASE + n * (NLAY * NRES) + l * NRES;
      stout(out, ib + 0, (double)i0, isbf);
      stout(out, ib + 1, (double)i1, isbf);
      stout(out, ib + 2, (double)i2, isbf);
    }
    for (int o = 32; o; o >>= 1) csum += __shfl_xor(csum, o);
    if (tid == 0 && csum != 0.0) atomAddD(commit, csum);
  } else if (tid >= 128) {
    int dd = tid - 128;
    int g = sbat[0];
    double acc = 0.0;
    for (int r = 0; r < 64; r++) {
      int gg = sbat[r];
      if (gg < 0) break;
      if (gg != g) {
        atomAddD(&xpool[(long)g * (DIM * NLAY) + l * DIM + dd], acc);
        acc = 0.0; g = gg;
      }
      acc += (double)hl[r * 132 + dd];
    }
    atomAddD(&xpool[(long)g * (DIM * NLAY) + l * DIM + dd], acc);
  }
}

// ---------- final: xpool + commit -> out ----------
__global__ __launch_bounds__(256) void k_out(const double* __restrict__ xpool, const double* __restrict__ commit,
                                             void* __restrict__ out, const int* __restrict__ flag) {
  int isbf = flag[0];
  long i = (long)blockIdx.x * 256 + threadIdx.x;
  const long NP = (long)NGRAPH * DIM * NLAY;
  if (i < NP) {
    stout(out, i, xpool[i], isbf);
  } else if (i == NP) {
    double c = commit[0] * (0.25 / ((double)N_NODES * (double)DIM));
    stout(out, NP + (long)N_NODES * DIM * NLAY, c, isbf);
  }
}

extern "C" void kernel_launch(void* const* d_in, const int* in_sizes, int n_in,
                              void* d_out, int out_size, void* d_ws, size_t ws_size,
                              hipStream_t stream) {
  const void* x = d_in[0];
  const int* ei = (const int*)d_in[1];
  const int* batch = (const int*)d_in[2];
  const void* W1 = d_in[3];
  const void* b1 = d_in[4];
  const void* W2 = d_in[5];
  const void* b2 = d_in[6];
  const void* gamma = d_in[7];
  const void* beta = d_in[8];
  const void* cb = d_in[9];

  double* w = (double*)d_ws;
  double* cbn = w;                      // 18,432
  double* G = cbn + 18432;              // 6,912
  double* stats = G + 6912;             // 256
  double* xpool = stats + 256;          // 196,608
  double* commit = xpool + (long)NGRAPH * DIM * NLAY;  // 1 (+1 pad)
  float* W1f = (float*)(commit + 2);    // 49,152
  float* W2f = W1f + 49152;             // 49,152
  float* b1f = W2f + 49152;             // 384
  float* b2f = b1f + 384;               // 384
  float* H  = b2f + 384;                // 12,800,000 (current h, fp32)
  float* T1 = H + 12800000;             // 12,800,000
  float* T2 = T1 + 12800000;            // 12,800,000
  int* ibuf = (int*)(T2 + 12800000);
  int* flag = ibuf;                     // 1 (+pad)
  int* deg = ibuf + 64;                 // N_NODES
  int* ofs = deg + N_NODES;             // N_NODES + 1
  int* cursor = ofs + N_NODES + 1;      // N_NODES
  int* csr = cursor + N_NODES;          // N_EDGES
  int* bsum = csr + N_EDGES;            // SCAN_NB (391)

  k_detect<<<1, 256, 0, stream>>>((const unsigned int*)x, flag);
  // zero accumulators (xpool + commit contiguous)
  hipMemsetAsync(xpool, 0, ((long)NGRAPH * DIM * NLAY + 1) * sizeof(double), stream);
  hipMemsetAsync(deg, 0, N_NODES * sizeof(int), stream);
  // fp32 copies of x and weights
  k_convert_f<<<50000, 256, 0, stream>>>(x, H, (long)N_NODES * DIM, flag);
  k_convert_f<<<192, 256, 0, stream>>>(W1, W1f, 49152, flag);
  k_convert_f<<<192, 256, 0, stream>>>(W2, W2f, 49152, flag);
  k_convert_f<<<2, 256, 0, stream>>>(b1, b1f, 384, flag);
  k_convert_f<<<2, 256, 0, stream>>>(b2, b2f, 384, flag);
  k_cbn<<<NLAY * NRES * NCODE, 64, 0, stream>>>(cb, cbn, flag);
  k_gram<<<NLAY * 48 * 48, 64, 0, stream>>>(cbn, G);
  // CSR build (once; reused all 3 layers)
  k_hist<<<(N_EDGES + 255) / 256, 256, 0, stream>>>(ei, deg);
  k_scan1<<<SCAN_NB, 256, 0, stream>>>(deg, bsum);
  k_scan2<<<1, 512, 0, stream>>>(bsum);
  k_scan3<<<SCAN_NB, 256, 0, stream>>>(deg, bsum, ofs, cursor);
  k_fill<<<(N_EDGES + 255) / 256, 256, 0, stream>>>(ei, cursor, csr);

  for (int l = 0; l < NLAY; l++) {
    // fused gather + GEMM1: T2 = relu(agg(H) @ W1 + b1)
    k_gathgemm1<<<GEMM_NB, 256, 0, stream>>>(H, ofs, csr, W1f + l * DIM * DIM, b1f + l * DIM, T2);
    // GEMM2: T1 = relu(T2 @ W2 + b2)
    k_gemm_relu_f<<<GEMM_NB, 256, 0, stream>>>(T2, W2f + l * DIM * DIM, b2f + l * DIM, T1);
    hipMemsetAsync(stats, 0, 256 * sizeof(double), stream);
    k_bn_stats<<<1024, 256, 0, stream>>>(T1, stats);
    // fused bn_prep + normalize + xs + hh + xpool + dotH + VQ
    k_post2<<<GEMM_NB, 256, 0, stream>>>(T1, stats, gamma, beta,
                                         cbn + (long)l * 48 * DIM, G + (long)l * 48 * 48,
                                         batch, d_out, xpool, commit, l, flag);
    // T1 becomes the new h
    float* t = H; H = T1; T1 = t;
  }
  k_out<<<769, 256, 0, stream>>>(xpool, commit, d_out, flag);
}

// Round 8
// 1710.971 us; speedup vs baseline: 1.3455x; 1.3455x over previous
//
#include <hip/hip_runtime.h>
#include <hip/hip_bf16.h>

#define N_NODES 100000
#define N_EDGES 1600000
#define DIM 128
#define NLAY 3
#define NRES 3
#define NCODE 16
#define NGRAPH 512
#define SCAN_NB ((N_NODES + 255) / 256)  // 391
#define GEMM_NB ((N_NODES + 63) / 64)    // 1563

using bf16 = __hip_bfloat16;

__device__ inline void atomAddD(double* p, double v) { unsafeAtomicAdd(p, v); }

// flag==1: external float-typed arrays are bf16; flag==0: they are fp32.
__device__ inline double ldx(const void* p, long i, int isbf) {
  if (isbf) return (double)__bfloat162float(((const bf16*)p)[i]);
  return (double)((const float*)p)[i];
}
__device__ inline void stout(void* p, long i, double v, int isbf) {
  if (isbf) ((bf16*)p)[i] = __float2bfloat16((float)v);
  else ((float*)p)[i] = (float)v;
}

// ---------- dtype detection: bf16 vs fp32 bit-pattern statistics ----------
__global__ void k_detect(const unsigned int* __restrict__ x, int* __restrict__ flag) {
  int tid = threadIdx.x;  // 256
  int cnt = 0;
  for (int j = tid; j < 1024; j += 256) {
    unsigned int u = x[j];
    int e = (u >> 7) & 0xFF;  // exponent field of the LOW u16 viewed as bf16
    cnt += (e >= 100 && e <= 135) ? 1 : 0;
  }
  __shared__ int sh[256];
  sh[tid] = cnt; __syncthreads();
  for (int s = 128; s; s >>= 1) { if (tid < s) sh[tid] += sh[tid + s]; __syncthreads(); }
  if (tid == 0) flag[0] = (sh[0] > 512) ? 1 : 0;
}

// ---------- external -> fp32 convert ----------
__global__ __launch_bounds__(256) void k_convert_f(const void* __restrict__ x, float* __restrict__ hf,
                                                   long n, const int* __restrict__ flag) {
  int isbf = flag[0];
  long i = (long)blockIdx.x * 256 + threadIdx.x;
  if (i < n) hf[i] = (float)ldx(x, i, isbf);
}

// ---------- CSR build: histogram ----------
__global__ __launch_bounds__(256) void k_hist(const int* __restrict__ ei, int* __restrict__ deg) {
  int e = blockIdx.x * 256 + threadIdx.x;
  if (e < N_EDGES) atomicAdd(&deg[ei[N_EDGES + e]], 1);
}

// ---------- CSR build: hierarchical exclusive scan (3 phases, all parallel) ----------
__global__ __launch_bounds__(256) void k_scan1(const int* __restrict__ deg, int* __restrict__ bsum) {
  int i = blockIdx.x * 256 + threadIdx.x;
  int v = (i < N_NODES) ? deg[i] : 0;
  for (int o = 32; o; o >>= 1) v += __shfl_xor(v, o);
  __shared__ int sh[4];
  if ((threadIdx.x & 63) == 0) sh[threadIdx.x >> 6] = v;
  __syncthreads();
  if (threadIdx.x == 0) bsum[blockIdx.x] = sh[0] + sh[1] + sh[2] + sh[3];
}

__global__ void k_scan2(int* __restrict__ bsum) {
  __shared__ int sh[512];
  int t = threadIdx.x;
  int v = (t < SCAN_NB) ? bsum[t] : 0;
  sh[t] = v; __syncthreads();
  for (int s = 1; s < 512; s <<= 1) {
    int add = (t >= s) ? sh[t - s] : 0;
    __syncthreads();
    sh[t] += add;
    __syncthreads();
  }
  if (t < SCAN_NB) bsum[t] = sh[t] - v;  // exclusive
}

__global__ __launch_bounds__(256) void k_scan3(const int* __restrict__ deg, const int* __restrict__ bsum,
                                               int* __restrict__ ofs, int* __restrict__ cursor) {
  int t = threadIdx.x;
  int i = blockIdx.x * 256 + t;
  int v = (i < N_NODES) ? deg[i] : 0;
  __shared__ int sh[256];
  sh[t] = v; __syncthreads();
  for (int s = 1; s < 256; s <<= 1) {
    int add = (t >= s) ? sh[t - s] : 0;
    __syncthreads();
    sh[t] += add;
    __syncthreads();
  }
  int excl = sh[t] - v + bsum[blockIdx.x];
  if (i < N_NODES) { ofs[i] = excl; cursor[i] = excl; }
  if (i == N_NODES - 1) ofs[N_NODES] = excl + v;
}

// ---------- CSR build: fill ----------
__global__ __launch_bounds__(256) void k_fill(const int* __restrict__ ei, int* __restrict__ cursor,
                                              int* __restrict__ csr) {
  int e = blockIdx.x * 256 + threadIdx.x;
  if (e < N_EDGES) {
    int d = ei[N_EDGES + e];
    int p = atomicAdd(&cursor[d], 1);
    csr[p] = ei[e];
  }
}

// ---------- normalize codebooks (fp64) ----------
__global__ void k_cbn(const void* __restrict__ cb, double* __restrict__ cbn, const int* __restrict__ flag) {
  int isbf = flag[0];
  int b = blockIdx.x, d = threadIdx.x;  // 144 blocks x 64 threads
  double v0 = ldx(cb, (long)b * DIM + d, isbf);
  double v1 = ldx(cb, (long)b * DIM + d + 64, isbf);
  double ss = v0 * v0 + v1 * v1;
  for (int o = 32; o; o >>= 1) ss += __shfl_xor(ss, o);
  double inv = 1.0 / sqrt(ss + 1e-12);
  cbn[b * DIM + d] = v0 * inv;
  cbn[b * DIM + d + 64] = v1 * inv;
}

// ---------- Gram matrices per layer ----------
__global__ void k_gram(const double* __restrict__ cbn, double* __restrict__ G) {
  int b = blockIdx.x, t = threadIdx.x;  // 3*48*48 blocks x 64
  int l = b / (48 * 48); int rem = b % (48 * 48); int a = rem / 48, c = rem % 48;
  const double* ra = cbn + (long)(l * 48 + a) * DIM;
  const double* rc = cbn + (long)(l * 48 + c) * DIM;
  double s = ra[t] * rc[t] + ra[t + 64] * rc[t + 64];
  for (int o = 32; o; o >>= 1) s += __shfl_xor(s, o);
  if (t == 0) G[b] = s;
}

// ---------- FUSED gather + GEMM1 + bias + relu (VERBATIM Round-7, harness-verified) ----------
__global__ __launch_bounds__(256) void k_gathgemm1(const float* __restrict__ hf,
                                                   const int* __restrict__ ofs,
                                                   const int* __restrict__ csr,
                                                   const float* __restrict__ W,
                                                   const float* __restrict__ bias,
                                                   float* __restrict__ out) {
  __shared__ float ul[64 * DIM];  // 32 KB
  int tid = threadIdx.x;
  long base = (long)blockIdx.x * 64;
  int wave = tid >> 6, lane = tid & 63;
  // gather phase: each wave produces 16 rows of the tile
  for (int i = 0; i < 16; i++) {
    int row = wave * 16 + i;
    long node = base + row;
    double accx = 0.0, accy = 0.0;
    if (node < N_NODES) {
      int beg = ofs[node], end = ofs[node + 1];
      float2 sv = *(const float2*)&hf[node * DIM + lane * 2];
      accx = (double)sv.x; accy = (double)sv.y;
      int j = beg;
      for (; j + 7 < end; j += 8) {
        int s0 = csr[j], s1 = csr[j + 1], s2 = csr[j + 2], s3 = csr[j + 3];
        int s4 = csr[j + 4], s5 = csr[j + 5], s6 = csr[j + 6], s7 = csr[j + 7];
        float2 v0 = *(const float2*)&hf[(long)s0 * DIM + lane * 2];
        float2 v1 = *(const float2*)&hf[(long)s1 * DIM + lane * 2];
        float2 v2 = *(const float2*)&hf[(long)s2 * DIM + lane * 2];
        float2 v3 = *(const float2*)&hf[(long)s3 * DIM + lane * 2];
        float2 v4 = *(const float2*)&hf[(long)s4 * DIM + lane * 2];
        float2 v5 = *(const float2*)&hf[(long)s5 * DIM + lane * 2];
        float2 v6 = *(const float2*)&hf[(long)s6 * DIM + lane * 2];
        float2 v7 = *(const float2*)&hf[(long)s7 * DIM + lane * 2];
        accx += (double)v0.x; accy += (double)v0.y;
        accx += (double)v1.x; accy += (double)v1.y;
        accx += (double)v2.x; accy += (double)v2.y;
        accx += (double)v3.x; accy += (double)v3.y;
        accx += (double)v4.x; accy += (double)v4.y;
        accx += (double)v5.x; accy += (double)v5.y;
        accx += (double)v6.x; accy += (double)v6.y;
        accx += (double)v7.x; accy += (double)v7.y;
      }
      for (; j < end; j++) {
        int s0 = csr[j];
        float2 v0 = *(const float2*)&hf[(long)s0 * DIM + lane * 2];
        accx += (double)v0.x; accy += (double)v0.y;
      }
    }
    *(float2*)&ul[row * DIM + lane * 2] = make_float2((float)accx, (float)accy);
  }
  __syncthreads();
  // GEMM phase — VERBATIM Round-3 body
  int cl = tid & 31;   // 32 col groups x 4 cols
  int rw = tid >> 5;   // 8 row groups x 8 rows
  int c0 = cl * 4;
  float acc[8][4] = {};
  for (int k = 0; k < DIM; k += 4) {
    float4 w0 = *(const float4*)&W[(k + 0) * DIM + c0];
    float4 w1 = *(const float4*)&W[(k + 1) * DIM + c0];
    float4 w2 = *(const float4*)&W[(k + 2) * DIM + c0];
    float4 w3 = *(const float4*)&W[(k + 3) * DIM + c0];
#pragma unroll
    for (int r = 0; r < 8; r++) {
      float4 u = *(const float4*)&ul[(rw * 8 + r) * DIM + k];
      acc[r][0] += u.x * w0.x + u.y * w1.x + u.z * w2.x + u.w * w3.x;
      acc[r][1] += u.x * w0.y + u.y * w1.y + u.z * w2.y + u.w * w3.y;
      acc[r][2] += u.x * w0.z + u.y * w1.z + u.z * w2.z + u.w * w3.z;
      acc[r][3] += u.x * w0.w + u.y * w1.w + u.z * w2.w + u.w * w3.w;
    }
  }
  float4 bv = *(const float4*)&bias[c0];
#pragma unroll
  for (int r = 0; r < 8; r++) {
    long row = base + rw * 8 + r;
    if (row < N_NODES) {
      float4 o;
      o.x = fmaxf(acc[r][0] + bv.x, 0.f);
      o.y = fmaxf(acc[r][1] + bv.y, 0.f);
      o.z = fmaxf(acc[r][2] + bv.z, 0.f);
      o.w = fmaxf(acc[r][3] + bv.w, 0.f);
      *(float4*)&out[row * DIM + c0] = o;
    }
  }
}

// ---------- fp32 GEMM + bias + relu: VERBATIM Round-3 kernel ----------
__global__ __launch_bounds__(256) void k_gemm_relu_f(const float* __restrict__ in,
                                                     const float* __restrict__ W,
                                                     const float* __restrict__ bias,
                                                     float* __restrict__ out) {
  __shared__ float ul[64 * DIM];  // 32 KB
  int tid = threadIdx.x;
  long base = (long)blockIdx.x * 64;
  for (int j = tid; j < 64 * DIM / 4; j += 256) {
    long row = base + (j >> 5);
    float4 v = make_float4(0.f, 0.f, 0.f, 0.f);
    if (row < N_NODES) v = *(const float4*)&in[base * DIM + (long)j * 4];
    *(float4*)&ul[j * 4] = v;
  }
  __syncthreads();
  int cl = tid & 31;
  int rw = tid >> 5;
  int c0 = cl * 4;
  float acc[8][4] = {};
  for (int k = 0; k < DIM; k += 4) {
    float4 w0 = *(const float4*)&W[(k + 0) * DIM + c0];
    float4 w1 = *(const float4*)&W[(k + 1) * DIM + c0];
    float4 w2 = *(const float4*)&W[(k + 2) * DIM + c0];
    float4 w3 = *(const float4*)&W[(k + 3) * DIM + c0];
#pragma unroll
    for (int r = 0; r < 8; r++) {
      float4 u = *(const float4*)&ul[(rw * 8 + r) * DIM + k];
      acc[r][0] += u.x * w0.x + u.y * w1.x + u.z * w2.x + u.w * w3.x;
      acc[r][1] += u.x * w0.y + u.y * w1.y + u.z * w2.y + u.w * w3.y;
      acc[r][2] += u.x * w0.z + u.y * w1.z + u.z * w2.z + u.w * w3.z;
      acc[r][3] += u.x * w0.w + u.y * w1.w + u.z * w2.w + u.w * w3.w;
    }
  }
  float4 bv = *(const float4*)&bias[c0];
#pragma unroll
  for (int r = 0; r < 8; r++) {
    long row = base + rw * 8 + r;
    if (row < N_NODES) {
      float4 o;
      o.x = fmaxf(acc[r][0] + bv.x, 0.f);
      o.y = fmaxf(acc[r][1] + bv.y, 0.f);
      o.z = fmaxf(acc[r][2] + bv.z, 0.f);
      o.w = fmaxf(acc[r][3] + bv.w, 0.f);
      *(float4*)&out[row * DIM + c0] = o;
    }
  }
}

// ---------- BN stats (fp32 in, fp64 accum) — VERBATIM Round-3 kernel ----------
__global__ __launch_bounds__(256) void k_bn_stats(const float* __restrict__ h, double* __restrict__ stats) {
  int tid = threadIdx.x; int col = tid & 127; int half = tid >> 7;
  double s = 0.0, s2 = 0.0;
  for (long r = blockIdx.x * 2 + half; r < N_NODES; r += 2048) {
    double v = (double)h[r * DIM + col];
    s += v; s2 += v * v;
  }
  __shared__ double ls[256], ls2[256];
  ls[tid] = s; ls2[tid] = s2;
  __syncthreads();
  if (tid < 128) {
    atomAddD(&stats[col], ls[tid] + ls[tid + 128]);
    atomAddD(&stats[DIM + col], ls2[tid] + ls2[tid + 128]);
  }
}

// ---------- BN prep (VERBATIM) ----------
__global__ void k_bn_prep(const double* __restrict__ stats, const void* __restrict__ gamma,
                          const void* __restrict__ beta, double* __restrict__ ss,
                          int l, const int* __restrict__ flag) {
  int isbf = flag[0];
  int d = threadIdx.x;  // 128
  double mean = stats[d] / (double)N_NODES;
  double var = stats[DIM + d] / (double)N_NODES - mean * mean;
  double sc = ldx(gamma, (long)l * DIM + d, isbf) / sqrt(var + 1e-5);
  ss[d] = sc;
  ss[DIM + d] = ldx(beta, (long)l * DIM + d, isbf) - mean * sc;
}

// ---------- slim fused post: normalize + xs + hh + xpool (VERBATIM Round-6, verified) ----------
__global__ __launch_bounds__(256) void k_post(float* __restrict__ h,
                                              const double* __restrict__ ss,
                                              const int* __restrict__ batch,
                                              void* __restrict__ out,
                                              double* __restrict__ xpool,
                                              double* __restrict__ hh,
                                              int l, const int* __restrict__ flag) {
  __shared__ float hl[64 * 132];   // normalized tile (fp32), padded
  __shared__ double hq[64 * 4];    // ||h||^2 quarter-partials
  __shared__ int sbat[64];
  int isbf = flag[0];
  int tid = threadIdx.x;
  long base = (long)blockIdx.x * 64;
  if (tid < 64) {
    long row = base + tid;
    sbat[tid] = (row < N_NODES) ? batch[row] : -1;
  }
  // phase 1: normalize (fp64 math) + write h + xs + stage tile
  int d = tid & 127, half = tid >> 7;
  double sc = ss[d], sh = ss[DIM + d];
  const long XS_BASE = (long)NGRAPH * DIM * NLAY;
  for (int rr = half; rr < 64; rr += 2) {
    long row = base + rr;
    float vf = 0.f;
    if (row < N_NODES) {
      double v = (double)h[row * DIM + d] * sc + sh;
      vf = (float)v;
      h[row * DIM + d] = vf;
      stout(out, XS_BASE + row * (DIM * NLAY) + l * DIM + d, v, isbf);
    }
    hl[rr * 132 + d] = vf;
  }
  __syncthreads();
  // phase 2: hh quarter-partials
  {
    int row = tid >> 2, q = tid & 3;
    double s2 = 0.0;
    const float* hp = &hl[row * 132 + q * 32];
#pragma unroll
    for (int i = 0; i < 32; i++) { double v = (double)hp[i]; s2 += v * v; }
    hq[row * 4 + q] = s2;
  }
  __syncthreads();
  // phase 3 (wave 0): hh write ; (waves 2-3): xpool segments
  if (tid < 64) {
    long n = base + tid;
    if (n < N_NODES) hh[n] = hq[tid * 4] + hq[tid * 4 + 1] + hq[tid * 4 + 2] + hq[tid * 4 + 3];
  } else if (tid >= 128) {
    int dd = tid - 128;
    int g = sbat[0];
    double acc = 0.0;
    for (int r = 0; r < 64; r++) {
      int gg = sbat[r];
      if (gg < 0) break;
      if (gg != g) {
        atomAddD(&xpool[(long)g * (DIM * NLAY) + l * DIM + dd], acc);
        acc = 0.0; g = gg;
      }
      acc += (double)hl[r * 132 + dd];
    }
    atomAddD(&xpool[(long)g * (DIM * NLAY) + l * DIM + dd], acc);
  }
}

// ---------- dotH = h @ cbn^T (48 cols), fp32 h, fp64 cbn LDS, fp64 accum, fp32 store ----------
// (VERBATIM Round-3 kernel — ID-path numerics proven against the harness reference)
__global__ __launch_bounds__(256) void k_dotH(const float* __restrict__ hn,
                                              const double* __restrict__ cbnL,
                                              float* __restrict__ dH) {
  __shared__ double cl[48 * 134];
  int tid = threadIdx.x;
  for (int j = tid; j < 48 * DIM; j += 256) { int c = j >> 7, k = j & 127; cl[c * 134 + k] = cbnL[j]; }
  __syncthreads();
  int ct = tid & 7; int c0 = ct * 6; int rt = tid >> 3;
  long r0 = (long)blockIdx.x * 64 + rt; long r1 = r0 + 32;
  long r0c = r0 < N_NODES ? r0 : (N_NODES - 1);
  long r1c = r1 < N_NODES ? r1 : (N_NODES - 1);
  double acc0[6] = {}, acc1[6] = {};
  for (int k = 0; k < DIM; k += 4) {
    float4 h0 = *(const float4*)&hn[r0c * DIM + k];
    float4 h1 = *(const float4*)&hn[r1c * DIM + k];
#pragma unroll
    for (int j = 0; j < 6; j++) {
      double2 ca = *(const double2*)&cl[(c0 + j) * 134 + k];
      double2 cb = *(const double2*)&cl[(c0 + j) * 134 + k + 2];
      acc0[j] += (double)h0.x * ca.x + (double)h0.y * ca.y + (double)h0.z * cb.x + (double)h0.w * cb.y;
      acc1[j] += (double)h1.x * ca.x + (double)h1.y * ca.y + (double)h1.z * cb.x + (double)h1.w * cb.y;
    }
  }
  if (r0 < N_NODES) {
#pragma unroll
    for (int j = 0; j < 6; j++) dH[r0 * 48 + c0 + j] = (float)acc0[j];
  }
  if (r1 < N_NODES) {
#pragma unroll
    for (int j = 0; j < 6; j++) dH[r1 * 48 + c0 + j] = (float)acc1[j];
  }
}

// ---------- VQ select via dotH & Gram; ids + commit (VERBATIM Round-3 kernel) ----------
__global__ __launch_bounds__(256) void k_vq(const float* __restrict__ dH, const double* __restrict__ hh,
                                            const double* __restrict__ G, void* __restrict__ out,
                                            double* __restrict__ commit, int l, const int* __restrict__ flag) {
  int isbf = flag[0];
  __shared__ double Gl[48 * 48];
  int tid = threadIdx.x;
  for (int j = tid; j < 48 * 48; j += 256) Gl[j] = G[j];
  __syncthreads();
  long n = (long)blockIdx.x * 256 + tid;
  double csum = 0.0;
  if (n < N_NODES) {
    double dh[48];
#pragma unroll
    for (int c = 0; c < 48; c++) dh[c] = (double)dH[n * 48 + c];
    int i0 = 0; double b0 = dh[0];
#pragma unroll
    for (int c = 1; c < 16; c++) { if (dh[c] > b0) { b0 = dh[c]; i0 = c; } }
    int i1 = 0; double b1 = dh[16] - Gl[i0 * 48 + 16];
#pragma unroll
    for (int c = 1; c < 16; c++) {
      double s = dh[16 + c] - Gl[i0 * 48 + 16 + c];
      if (s > b1) { b1 = s; i1 = c; }
    }
    int i2 = 0; double b2 = dh[32] - Gl[i0 * 48 + 32] - Gl[(16 + i1) * 48 + 32];
#pragma unroll
    for (int c = 1; c < 16; c++) {
      double s = dh[32 + c] - Gl[i0 * 48 + 32 + c] - Gl[(16 + i1) * 48 + 32 + c];
      if (s > b2) { b2 = s; i2 = c; }
    }
    double r1s = hh[n] - 2.0 * b0 + Gl[i0 * 48 + i0];
    double r2s = r1s - 2.0 * b1 + Gl[(16 + i1) * 48 + 16 + i1];
    double r3s = r2s - 2.0 * b2 + Gl[(32 + i2) * 48 + 32 + i2];
    csum = r1s + r2s + r3s;
    const long IDS_BASE = (long)NGRAPH * DIM * NLAY + (long)N_NODES * DIM * NLAY + 1;
    long base = IDS_BASE + n * (NLAY * NRES) + l * NRES;
    stout(out, base + 0, (double)i0, isbf);
    stout(out, base + 1, (double)i1, isbf);
    stout(out, base + 2, (double)i2, isbf);
  }
  for (int o = 32; o; o >>= 1) csum += __shfl_xor(csum, o);
  if ((tid & 63) == 0 && csum != 0.0) atomAddD(commit, csum);
}

// ---------- final: xpool + commit -> out ----------
__global__ __launch_bounds__(256) void k_out(const double* __restrict__ xpool, const double* __restrict__ commit,
                                             void* __restrict__ out, const int* __restrict__ flag) {
  int isbf = flag[0];
  long i = (long)blockIdx.x * 256 + threadIdx.x;
  const long NP = (long)NGRAPH * DIM * NLAY;
  if (i < NP) {
    stout(out, i, xpool[i], isbf);
  } else if (i == NP) {
    double c = commit[0] * (0.25 / ((double)N_NODES * (double)DIM));
    stout(out, NP + (long)N_NODES * DIM * NLAY, c, isbf);
  }
}

extern "C" void kernel_launch(void* const* d_in, const int* in_sizes, int n_in,
                              void* d_out, int out_size, void* d_ws, size_t ws_size,
                              hipStream_t stream) {
  const void* x = d_in[0];
  const int* ei = (const int*)d_in[1];
  const int* batch = (const int*)d_in[2];
  const void* W1 = d_in[3];
  const void* b1 = d_in[4];
  const void* W2 = d_in[5];
  const void* b2 = d_in[6];
  const void* gamma = d_in[7];
  const void* beta = d_in[8];
  const void* cb = d_in[9];

  double* w = (double*)d_ws;
  double* cbn = w;                      // 18,432
  double* G = cbn + 18432;              // 6,912
  double* stats = G + 6912;             // 256
  double* ss = stats + 256;             // 256
  double* hh = ss + 256;                // 100,000
  double* xpool = hh + N_NODES;         // 196,608
  double* commit = xpool + (long)NGRAPH * DIM * NLAY;  // 1 (+1 pad)
  float* W1f = (float*)(commit + 2);    // 49,152
  float* W2f = W1f + 49152;             // 49,152
  float* b1f = W2f + 49152;             // 384
  float* b2f = b1f + 384;               // 384
  float* H  = b2f + 384;                // 12,800,000 (current h, fp32)
  float* T1 = H + 12800000;             // 12,800,000
  float* T2 = T1 + 12800000;            // 12,800,000
  float* dH = T2 + 12800000;            // 4,800,000
  int* ibuf = (int*)(dH + 4800000);
  int* flag = ibuf;                     // 1 (+pad)
  int* deg = ibuf + 64;                 // N_NODES
  int* ofs = deg + N_NODES;             // N_NODES + 1
  int* cursor = ofs + N_NODES + 1;      // N_NODES
  int* csr = cursor + N_NODES;          // N_EDGES
  int* bsum = csr + N_EDGES;            // SCAN_NB (391)

  k_detect<<<1, 256, 0, stream>>>((const unsigned int*)x, flag);
  // zero accumulators (xpool + commit contiguous)
  hipMemsetAsync(xpool, 0, ((long)NGRAPH * DIM * NLAY + 1) * sizeof(double), stream);
  hipMemsetAsync(deg, 0, N_NODES * sizeof(int), stream);
  // fp32 copies of x and weights
  k_convert_f<<<50000, 256, 0, stream>>>(x, H, (long)N_NODES * DIM, flag);
  k_convert_f<<<192, 256, 0, stream>>>(W1, W1f, 49152, flag);
  k_convert_f<<<192, 256, 0, stream>>>(W2, W2f, 49152, flag);
  k_convert_f<<<2, 256, 0, stream>>>(b1, b1f, 384, flag);
  k_convert_f<<<2, 256, 0, stream>>>(b2, b2f, 384, flag);
  k_cbn<<<NLAY * NRES * NCODE, 64, 0, stream>>>(cb, cbn, flag);
  k_gram<<<NLAY * 48 * 48, 64, 0, stream>>>(cbn, G);
  // CSR build (once; reused all 3 layers)
  k_hist<<<(N_EDGES + 255) / 256, 256, 0, stream>>>(ei, deg);
  k_scan1<<<SCAN_NB, 256, 0, stream>>>(deg, bsum);
  k_scan2<<<1, 512, 0, stream>>>(bsum);
  k_scan3<<<SCAN_NB, 256, 0, stream>>>(deg, bsum, ofs, cursor);
  k_fill<<<(N_EDGES + 255) / 256, 256, 0, stream>>>(ei, cursor, csr);

  for (int l = 0; l < NLAY; l++) {
    // fused gather + GEMM1: T2 = relu(agg(H) @ W1 + b1)
    k_gathgemm1<<<GEMM_NB, 256, 0, stream>>>(H, ofs, csr, W1f + l * DIM * DIM, b1f + l * DIM, T2);
    // GEMM2: T1 = relu(T2 @ W2 + b2)
    k_gemm_relu_f<<<GEMM_NB, 256, 0, stream>>>(T2, W2f + l * DIM * DIM, b2f + l * DIM, T1);
    hipMemsetAsync(stats, 0, 256 * sizeof(double), stream);
    k_bn_stats<<<1024, 256, 0, stream>>>(T1, stats);
    k_bn_prep<<<1, 128, 0, stream>>>(stats, gamma, beta, ss, l, flag);
    k_post<<<GEMM_NB, 256, 0, stream>>>(T1, ss, batch, d_out, xpool, hh, l, flag);
    k_dotH<<<1563, 256, 0, stream>>>(T1, cbn + (long)l * 48 * DIM, dH);
    k_vq<<<391, 256, 0, stream>>>(dH, hh, G + l * 48 * 48, d_out, commit, l, flag);
    // T1 becomes the new h; T2 stays scratch
    float* t = H; H = T1; T1 = t;
  }
  k_out<<<769, 256, 0, stream>>>(xpool, commit, d_out, flag);
}

// Round 9
// 1596.980 us; speedup vs baseline: 1.4416x; 1.0714x over previous
//
#include <hip/hip_runtime.h>
#include <hip/hip_bf16.h>

#define N_NODES 100000
#define N_EDGES 1600000
#define DIM 128
#define NLAY 3
#define NRES 3
#define NCODE 16
#define NGRAPH 512
#define SCAN_NB ((N_NODES + 255) / 256)  // 391
#define GEMM_NB ((N_NODES + 63) / 64)    // 1563

using bf16 = __hip_bfloat16;

__device__ inline void atomAddD(double* p, double v) { unsafeAtomicAdd(p, v); }

// flag==1: external float-typed arrays are bf16; flag==0: they are fp32.
__device__ inline double ldx(const void* p, long i, int isbf) {
  if (isbf) return (double)__bfloat162float(((const bf16*)p)[i]);
  return (double)((const float*)p)[i];
}
__device__ inline void stout(void* p, long i, double v, int isbf) {
  if (isbf) ((bf16*)p)[i] = __float2bfloat16((float)v);
  else ((float*)p)[i] = (float)v;
}

// ---------- dtype detection: bf16 vs fp32 bit-pattern statistics ----------
__global__ void k_detect(const unsigned int* __restrict__ x, int* __restrict__ flag) {
  int tid = threadIdx.x;  // 256
  int cnt = 0;
  for (int j = tid; j < 1024; j += 256) {
    unsigned int u = x[j];
    int e = (u >> 7) & 0xFF;  // exponent field of the LOW u16 viewed as bf16
    cnt += (e >= 100 && e <= 135) ? 1 : 0;
  }
  __shared__ int sh[256];
  sh[tid] = cnt; __syncthreads();
  for (int s = 128; s; s >>= 1) { if (tid < s) sh[tid] += sh[tid + s]; __syncthreads(); }
  if (tid == 0) flag[0] = (sh[0] > 512) ? 1 : 0;
}

// ---------- external -> fp32 convert ----------
__global__ __launch_bounds__(256) void k_convert_f(const void* __restrict__ x, float* __restrict__ hf,
                                                   long n, const int* __restrict__ flag) {
  int isbf = flag[0];
  long i = (long)blockIdx.x * 256 + threadIdx.x;
  if (i < n) hf[i] = (float)ldx(x, i, isbf);
}

// ---------- CSR build: histogram ----------
__global__ __launch_bounds__(256) void k_hist(const int* __restrict__ ei, int* __restrict__ deg) {
  int e = blockIdx.x * 256 + threadIdx.x;
  if (e < N_EDGES) atomicAdd(&deg[ei[N_EDGES + e]], 1);
}

// ---------- CSR build: hierarchical exclusive scan (3 phases, all parallel) ----------
__global__ __launch_bounds__(256) void k_scan1(const int* __restrict__ deg, int* __restrict__ bsum) {
  int i = blockIdx.x * 256 + threadIdx.x;
  int v = (i < N_NODES) ? deg[i] : 0;
  for (int o = 32; o; o >>= 1) v += __shfl_xor(v, o);
  __shared__ int sh[4];
  if ((threadIdx.x & 63) == 0) sh[threadIdx.x >> 6] = v;
  __syncthreads();
  if (threadIdx.x == 0) bsum[blockIdx.x] = sh[0] + sh[1] + sh[2] + sh[3];
}

__global__ void k_scan2(int* __restrict__ bsum) {
  __shared__ int sh[512];
  int t = threadIdx.x;
  int v = (t < SCAN_NB) ? bsum[t] : 0;
  sh[t] = v; __syncthreads();
  for (int s = 1; s < 512; s <<= 1) {
    int add = (t >= s) ? sh[t - s] : 0;
    __syncthreads();
    sh[t] += add;
    __syncthreads();
  }
  if (t < SCAN_NB) bsum[t] = sh[t] - v;  // exclusive
}

__global__ __launch_bounds__(256) void k_scan3(const int* __restrict__ deg, const int* __restrict__ bsum,
                                               int* __restrict__ ofs, int* __restrict__ cursor) {
  int t = threadIdx.x;
  int i = blockIdx.x * 256 + t;
  int v = (i < N_NODES) ? deg[i] : 0;
  __shared__ int sh[256];
  sh[t] = v; __syncthreads();
  for (int s = 1; s < 256; s <<= 1) {
    int add = (t >= s) ? sh[t - s] : 0;
    __syncthreads();
    sh[t] += add;
    __syncthreads();
  }
  int excl = sh[t] - v + bsum[blockIdx.x];
  if (i < N_NODES) { ofs[i] = excl; cursor[i] = excl; }
  if (i == N_NODES - 1) ofs[N_NODES] = excl + v;
}

// ---------- CSR build: fill ----------
__global__ __launch_bounds__(256) void k_fill(const int* __restrict__ ei, int* __restrict__ cursor,
                                              int* __restrict__ csr) {
  int e = blockIdx.x * 256 + threadIdx.x;
  if (e < N_EDGES) {
    int d = ei[N_EDGES + e];
    int p = atomicAdd(&cursor[d], 1);
    csr[p] = ei[e];
  }
}

// ---------- gather: out[n] = h[n] + sum_{j in in(n)} h[src_j] (VERBATIM R6) ----------
__global__ __launch_bounds__(256) void k_gather(const float* __restrict__ hf,
                                                const int* __restrict__ ofs,
                                                const int* __restrict__ csr,
                                                float* __restrict__ outQ) {
  int node = blockIdx.x * 4 + (threadIdx.x >> 6);
  int lane = threadIdx.x & 63;
  int beg = ofs[node], end = ofs[node + 1];
  float2 sv = *(const float2*)&hf[(long)node * DIM + lane * 2];
  double accx = (double)sv.x, accy = (double)sv.y;
  int j = beg;
  for (; j + 3 < end; j += 4) {
    int s0 = csr[j], s1 = csr[j + 1], s2 = csr[j + 2], s3 = csr[j + 3];
    float2 v0 = *(const float2*)&hf[(long)s0 * DIM + lane * 2];
    float2 v1 = *(const float2*)&hf[(long)s1 * DIM + lane * 2];
    float2 v2 = *(const float2*)&hf[(long)s2 * DIM + lane * 2];
    float2 v3 = *(const float2*)&hf[(long)s3 * DIM + lane * 2];
    accx += (double)v0.x; accy += (double)v0.y;
    accx += (double)v1.x; accy += (double)v1.y;
    accx += (double)v2.x; accy += (double)v2.y;
    accx += (double)v3.x; accy += (double)v3.y;
  }
  for (; j < end; j++) {
    int s0 = csr[j];
    float2 v0 = *(const float2*)&hf[(long)s0 * DIM + lane * 2];
    accx += (double)v0.x; accy += (double)v0.y;
  }
  *(float2*)&outQ[(long)node * DIM + lane * 2] = make_float2((float)accx, (float)accy);
}

// ---------- normalize codebooks (fp64) ----------
__global__ void k_cbn(const void* __restrict__ cb, double* __restrict__ cbn, const int* __restrict__ flag) {
  int isbf = flag[0];
  int b = blockIdx.x, d = threadIdx.x;  // 144 blocks x 64 threads
  double v0 = ldx(cb, (long)b * DIM + d, isbf);
  double v1 = ldx(cb, (long)b * DIM + d + 64, isbf);
  double ss = v0 * v0 + v1 * v1;
  for (int o = 32; o; o >>= 1) ss += __shfl_xor(ss, o);
  double inv = 1.0 / sqrt(ss + 1e-12);
  cbn[b * DIM + d] = v0 * inv;
  cbn[b * DIM + d + 64] = v1 * inv;
}

// ---------- Gram matrices per layer ----------
__global__ void k_gram(const double* __restrict__ cbn, double* __restrict__ G) {
  int b = blockIdx.x, t = threadIdx.x;  // 3*48*48 blocks x 64
  int l = b / (48 * 48); int rem = b % (48 * 48); int a = rem / 48, c = rem % 48;
  const double* ra = cbn + (long)(l * 48 + a) * DIM;
  const double* rc = cbn + (long)(l * 48 + c) * DIM;
  double s = ra[t] * rc[t] + ra[t + 64] * rc[t + 64];
  for (int o = 32; o; o >>= 1) s += __shfl_xor(s, o);
  if (t == 0) G[b] = s;
}

// ---------- fp32 GEMM + bias + relu: VERBATIM Round-3 kernel ----------
__global__ __launch_bounds__(256) void k_gemm_relu_f(const float* __restrict__ in,
                                                     const float* __restrict__ W,
                                                     const float* __restrict__ bias,
                                                     float* __restrict__ out) {
  __shared__ float ul[64 * DIM];  // 32 KB
  int tid = threadIdx.x;
  long base = (long)blockIdx.x * 64;
  for (int j = tid; j < 64 * DIM / 4; j += 256) {
    long row = base + (j >> 5);
    float4 v = make_float4(0.f, 0.f, 0.f, 0.f);
    if (row < N_NODES) v = *(const float4*)&in[base * DIM + (long)j * 4];
    *(float4*)&ul[j * 4] = v;
  }
  __syncthreads();
  int cl = tid & 31;
  int rw = tid >> 5;
  int c0 = cl * 4;
  float acc[8][4] = {};
  for (int k = 0; k < DIM; k += 4) {
    float4 w0 = *(const float4*)&W[(k + 0) * DIM + c0];
    float4 w1 = *(const float4*)&W[(k + 1) * DIM + c0];
    float4 w2 = *(const float4*)&W[(k + 2) * DIM + c0];
    float4 w3 = *(const float4*)&W[(k + 3) * DIM + c0];
#pragma unroll
    for (int r = 0; r < 8; r++) {
      float4 u = *(const float4*)&ul[(rw * 8 + r) * DIM + k];
      acc[r][0] += u.x * w0.x + u.y * w1.x + u.z * w2.x + u.w * w3.x;
      acc[r][1] += u.x * w0.y + u.y * w1.y + u.z * w2.y + u.w * w3.y;
      acc[r][2] += u.x * w0.z + u.y * w1.z + u.z * w2.z + u.w * w3.z;
      acc[r][3] += u.x * w0.w + u.y * w1.w + u.z * w2.w + u.w * w3.w;
    }
  }
  float4 bv = *(const float4*)&bias[c0];
#pragma unroll
  for (int r = 0; r < 8; r++) {
    long row = base + rw * 8 + r;
    if (row < N_NODES) {
      float4 o;
      o.x = fmaxf(acc[r][0] + bv.x, 0.f);
      o.y = fmaxf(acc[r][1] + bv.y, 0.f);
      o.z = fmaxf(acc[r][2] + bv.z, 0.f);
      o.w = fmaxf(acc[r][3] + bv.w, 0.f);
      *(float4*)&out[row * DIM + c0] = o;
    }
  }
}

// ---------- GEMM2 = verbatim GEMM body + fp64 BN-stats epilogue (8-slab atomics) ----------
// Inner loop and store expressions byte-identical to k_gemm_relu_f; the epilogue only
// accumulates the already-stored fp32 outputs in fp64 (reorder ~1e-13 — safe regime).
__global__ __launch_bounds__(256) void k_gemm_relu_stats(const float* __restrict__ in,
                                                         const float* __restrict__ W,
                                                         const float* __restrict__ bias,
                                                         float* __restrict__ out,
                                                         double* __restrict__ stats8) {
  __shared__ __align__(16) float ul[64 * DIM];  // 32 KB
  int tid = threadIdx.x;
  long base = (long)blockIdx.x * 64;
  for (int j = tid; j < 64 * DIM / 4; j += 256) {
    long row = base + (j >> 5);
    float4 v = make_float4(0.f, 0.f, 0.f, 0.f);
    if (row < N_NODES) v = *(const float4*)&in[base * DIM + (long)j * 4];
    *(float4*)&ul[j * 4] = v;
  }
  __syncthreads();
  int cl = tid & 31;
  int rw = tid >> 5;
  int c0 = cl * 4;
  float acc[8][4] = {};
  for (int k = 0; k < DIM; k += 4) {
    float4 w0 = *(const float4*)&W[(k + 0) * DIM + c0];
    float4 w1 = *(const float4*)&W[(k + 1) * DIM + c0];
    float4 w2 = *(const float4*)&W[(k + 2) * DIM + c0];
    float4 w3 = *(const float4*)&W[(k + 3) * DIM + c0];
#pragma unroll
    for (int r = 0; r < 8; r++) {
      float4 u = *(const float4*)&ul[(rw * 8 + r) * DIM + k];
      acc[r][0] += u.x * w0.x + u.y * w1.x + u.z * w2.x + u.w * w3.x;
      acc[r][1] += u.x * w0.y + u.y * w1.y + u.z * w2.y + u.w * w3.y;
      acc[r][2] += u.x * w0.z + u.y * w1.z + u.z * w2.z + u.w * w3.z;
      acc[r][3] += u.x * w0.w + u.y * w1.w + u.z * w2.w + u.w * w3.w;
    }
  }
  float4 bv = *(const float4*)&bias[c0];
  double cs0 = 0.0, cs1 = 0.0, cs2 = 0.0, cs3 = 0.0;
  double q0 = 0.0, q1 = 0.0, q2 = 0.0, q3 = 0.0;
#pragma unroll
  for (int r = 0; r < 8; r++) {
    long row = base + rw * 8 + r;
    if (row < N_NODES) {
      float4 o;
      o.x = fmaxf(acc[r][0] + bv.x, 0.f);
      o.y = fmaxf(acc[r][1] + bv.y, 0.f);
      o.z = fmaxf(acc[r][2] + bv.z, 0.f);
      o.w = fmaxf(acc[r][3] + bv.w, 0.f);
      *(float4*)&out[row * DIM + c0] = o;
      double dx = (double)o.x, dy = (double)o.y, dz = (double)o.z, dw = (double)o.w;
      cs0 += dx; q0 += dx * dx;
      cs1 += dy; q1 += dy * dy;
      cs2 += dz; q2 += dz * dz;
      cs3 += dw; q3 += dw * dw;
    }
  }
  __syncthreads();  // ul reads complete; reuse as fp64 reduction space
  double* sred = (double*)ul;  // 4096 doubles available, need 2048
  sred[rw * 128 + c0 + 0] = cs0; sred[1024 + rw * 128 + c0 + 0] = q0;
  sred[rw * 128 + c0 + 1] = cs1; sred[1024 + rw * 128 + c0 + 1] = q1;
  sred[rw * 128 + c0 + 2] = cs2; sred[1024 + rw * 128 + c0 + 2] = q2;
  sred[rw * 128 + c0 + 3] = cs3; sred[1024 + rw * 128 + c0 + 3] = q3;
  __syncthreads();
  if (tid < 128) {
    double S = 0.0, S2 = 0.0;
#pragma unroll
    for (int i = 0; i < 8; i++) { S += sred[i * 128 + tid]; S2 += sred[1024 + i * 128 + tid]; }
    int slab = blockIdx.x & 7;
    atomAddD(&stats8[slab * 256 + tid], S);
    atomAddD(&stats8[slab * 256 + 128 + tid], S2);
  }
}

// ---------- fused post: bn_prep(8-slab) + normalize + xs + hh + xpool ----------
// normalize/hq/xpool body VERBATIM R6 k_post; bn_prep fold proven in R7 post2.
__global__ __launch_bounds__(256) void k_post(float* __restrict__ h,
                                              const double* __restrict__ stats8,
                                              const void* __restrict__ gamma,
                                              const void* __restrict__ beta,
                                              const int* __restrict__ batch,
                                              void* __restrict__ out,
                                              double* __restrict__ xpool,
                                              double* __restrict__ hh,
                                              int l, const int* __restrict__ flag) {
  __shared__ float hl[64 * 132];   // normalized tile (fp32), padded
  __shared__ double hq[64 * 4];    // ||h||^2 quarter-partials
  __shared__ double ssl[256];      // BN scale/shift
  __shared__ int sbat[64];
  int isbf = flag[0];
  int tid = threadIdx.x;
  long base = (long)blockIdx.x * 64;
  if (tid < 128) {
    double sum = 0.0, sumsq = 0.0;
#pragma unroll
    for (int s8 = 0; s8 < 8; s8++) { sum += stats8[s8 * 256 + tid]; sumsq += stats8[s8 * 256 + 128 + tid]; }
    double mean = sum / (double)N_NODES;
    double var = sumsq / (double)N_NODES - mean * mean;
    double sc = ldx(gamma, (long)l * DIM + tid, isbf) / sqrt(var + 1e-5);
    ssl[tid] = sc;
    ssl[DIM + tid] = ldx(beta, (long)l * DIM + tid, isbf) - mean * sc;
  }
  if (tid < 64) {
    long row = base + tid;
    sbat[tid] = (row < N_NODES) ? batch[row] : -1;
  }
  __syncthreads();
  // phase 1: normalize (fp64 math) + write h + xs + stage tile
  int d = tid & 127, half = tid >> 7;
  double sc = ssl[d], sh = ssl[DIM + d];
  const long XS_BASE = (long)NGRAPH * DIM * NLAY;
  for (int rr = half; rr < 64; rr += 2) {
    long row = base + rr;
    float vf = 0.f;
    if (row < N_NODES) {
      double v = (double)h[row * DIM + d] * sc + sh;
      vf = (float)v;
      h[row * DIM + d] = vf;
      stout(out, XS_BASE + row * (DIM * NLAY) + l * DIM + d, v, isbf);
    }
    hl[rr * 132 + d] = vf;
  }
  __syncthreads();
  // phase 2: hh quarter-partials
  {
    int row = tid >> 2, q = tid & 3;
    double s2 = 0.0;
    const float* hp = &hl[row * 132 + q * 32];
#pragma unroll
    for (int i = 0; i < 32; i++) { double v = (double)hp[i]; s2 += v * v; }
    hq[row * 4 + q] = s2;
  }
  __syncthreads();
  // phase 3 (wave 0): hh write ; (waves 2-3): xpool segments
  if (tid < 64) {
    long n = base + tid;
    if (n < N_NODES) hh[n] = hq[tid * 4] + hq[tid * 4 + 1] + hq[tid * 4 + 2] + hq[tid * 4 + 3];
  } else if (tid >= 128) {
    int dd = tid - 128;
    int g = sbat[0];
    double acc = 0.0;
    for (int r = 0; r < 64; r++) {
      int gg = sbat[r];
      if (gg < 0) break;
      if (gg != g) {
        atomAddD(&xpool[(long)g * (DIM * NLAY) + l * DIM + dd], acc);
        acc = 0.0; g = gg;
      }
      acc += (double)hl[r * 132 + dd];
    }
    atomAddD(&xpool[(long)g * (DIM * NLAY) + l * DIM + dd], acc);
  }
}

// ---------- dotH = h @ cbn^T (48 cols), fp32 h, fp64 cbn LDS, fp64 accum, fp32 store ----------
// (VERBATIM Round-3 kernel — ID-path numerics proven against the harness reference)
__global__ __launch_bounds__(256) void k_dotH(const float* __restrict__ hn,
                                              const double* __restrict__ cbnL,
                                              float* __restrict__ dH) {
  __shared__ double cl[48 * 134];
  int tid = threadIdx.x;
  for (int j = tid; j < 48 * DIM; j += 256) { int c = j >> 7, k = j & 127; cl[c * 134 + k] = cbnL[j]; }
  __syncthreads();
  int ct = tid & 7; int c0 = ct * 6; int rt = tid >> 3;
  long r0 = (long)blockIdx.x * 64 + rt; long r1 = r0 + 32;
  long r0c = r0 < N_NODES ? r0 : (N_NODES - 1);
  long r1c = r1 < N_NODES ? r1 : (N_NODES - 1);
  double acc0[6] = {}, acc1[6] = {};
  for (int k = 0; k < DIM; k += 4) {
    float4 h0 = *(const float4*)&hn[r0c * DIM + k];
    float4 h1 = *(const float4*)&hn[r1c * DIM + k];
#pragma unroll
    for (int j = 0; j < 6; j++) {
      double2 ca = *(const double2*)&cl[(c0 + j) * 134 + k];
      double2 cb = *(const double2*)&cl[(c0 + j) * 134 + k + 2];
      acc0[j] += (double)h0.x * ca.x + (double)h0.y * ca.y + (double)h0.z * cb.x + (double)h0.w * cb.y;
      acc1[j] += (double)h1.x * ca.x + (double)h1.y * ca.y + (double)h1.z * cb.x + (double)h1.w * cb.y;
    }
  }
  if (r0 < N_NODES) {
#pragma unroll
    for (int j = 0; j < 6; j++) dH[r0 * 48 + c0 + j] = (float)acc0[j];
  }
  if (r1 < N_NODES) {
#pragma unroll
    for (int j = 0; j < 6; j++) dH[r1 * 48 + c0 + j] = (float)acc1[j];
  }
}

// ---------- VQ select via dotH & Gram; ids + commit (VERBATIM Round-3 kernel) ----------
__global__ __launch_bounds__(256) void k_vq(const float* __restrict__ dH, const double* __restrict__ hh,
                                            const double* __restrict__ G, void* __restrict__ out,
                                            double* __restrict__ commit, int l, const int* __restrict__ flag) {
  int isbf = flag[0];
  __shared__ double Gl[48 * 48];
  int tid = threadIdx.x;
  for (int j = tid; j < 48 * 48; j += 256) Gl[j] = G[j];
  __syncthreads();
  long n = (long)blockIdx.x * 256 + tid;
  double csum = 0.0;
  if (n < N_NODES) {
    double dh[48];
#pragma unroll
    for (int c = 0; c < 48; c++) dh[c] = (double)dH[n * 48 + c];
    int i0 = 0; double b0 = dh[0];
#pragma unroll
    for (int c = 1; c < 16; c++) { if (dh[c] > b0) { b0 = dh[c]; i0 = c; } }
    int i1 = 0; double b1 = dh[16] - Gl[i0 * 48 + 16];
#pragma unroll
    for (int c = 1; c < 16; c++) {
      double s = dh[16 + c] - Gl[i0 * 48 + 16 + c];
      if (s > b1) { b1 = s; i1 = c; }
    }
    int i2 = 0; double b2 = dh[32] - Gl[i0 * 48 + 32] - Gl[(16 + i1) * 48 + 32];
#pragma unroll
    for (int c = 1; c < 16; c++) {
      double s = dh[32 + c] - Gl[i0 * 48 + 32 + c] - Gl[(16 + i1) * 48 + 32 + c];
      if (s > b2) { b2 = s; i2 = c; }
    }
    double r1s = hh[n] - 2.0 * b0 + Gl[i0 * 48 + i0];
    double r2s = r1s - 2.0 * b1 + Gl[(16 + i1) * 48 + 16 + i1];
    double r3s = r2s - 2.0 * b2 + Gl[(32 + i2) * 48 + 32 + i2];
    csum = r1s + r2s + r3s;
    const long IDS_BASE = (long)NGRAPH * DIM * NLAY + (long)N_NODES * DIM * NLAY + 1;
    long base = IDS_BASE + n * (NLAY * NRES) + l * NRES;
    stout(out, base + 0, (double)i0, isbf);
    stout(out, base + 1, (double)i1, isbf);
    stout(out, base + 2, (double)i2, isbf);
  }
  for (int o = 32; o; o >>= 1) csum += __shfl_xor(csum, o);
  if ((tid & 63) == 0 && csum != 0.0) atomAddD(commit, csum);
}

// ---------- final: xpool + commit -> out ----------
__global__ __launch_bounds__(256) void k_out(const double* __restrict__ xpool, const double* __restrict__ commit,
                                             void* __restrict__ out, const int* __restrict__ flag) {
  int isbf = flag[0];
  long i = (long)blockIdx.x * 256 + threadIdx.x;
  const long NP = (long)NGRAPH * DIM * NLAY;
  if (i < NP) {
    stout(out, i, xpool[i], isbf);
  } else if (i == NP) {
    double c = commit[0] * (0.25 / ((double)N_NODES * (double)DIM));
    stout(out, NP + (long)N_NODES * DIM * NLAY, c, isbf);
  }
}

extern "C" void kernel_launch(void* const* d_in, const int* in_sizes, int n_in,
                              void* d_out, int out_size, void* d_ws, size_t ws_size,
                              hipStream_t stream) {
  const void* x = d_in[0];
  const int* ei = (const int*)d_in[1];
  const int* batch = (const int*)d_in[2];
  const void* W1 = d_in[3];
  const void* b1 = d_in[4];
  const void* W2 = d_in[5];
  const void* b2 = d_in[6];
  const void* gamma = d_in[7];
  const void* beta = d_in[8];
  const void* cb = d_in[9];

  double* w = (double*)d_ws;
  double* cbn = w;                      // 18,432
  double* G = cbn + 18432;              // 6,912
  double* stats8 = G + 6912;            // 2,048 (8 slabs x 256)
  double* hh = stats8 + 2048;           // 100,000
  double* xpool = hh + N_NODES;         // 196,608
  double* commit = xpool + (long)NGRAPH * DIM * NLAY;  // 1 (+1 pad)
  float* W1f = (float*)(commit + 2);    // 49,152
  float* W2f = W1f + 49152;             // 49,152
  float* b1f = W2f + 49152;             // 384
  float* b2f = b1f + 384;               // 384
  float* H  = b2f + 384;                // 12,800,000 (current h, fp32)
  float* T1 = H + 12800000;             // 12,800,000
  float* T2 = T1 + 12800000;            // 12,800,000
  float* dH = T2 + 12800000;            // 4,800,000
  int* ibuf = (int*)(dH + 4800000);
  int* flag = ibuf;                     // 1 (+pad)
  int* deg = ibuf + 64;                 // N_NODES
  int* ofs = deg + N_NODES;             // N_NODES + 1
  int* cursor = ofs + N_NODES + 1;      // N_NODES
  int* csr = cursor + N_NODES;          // N_EDGES
  int* bsum = csr + N_EDGES;            // SCAN_NB (391)

  k_detect<<<1, 256, 0, stream>>>((const unsigned int*)x, flag);
  // zero accumulators (xpool + commit contiguous)
  hipMemsetAsync(xpool, 0, ((long)NGRAPH * DIM * NLAY + 1) * sizeof(double), stream);
  hipMemsetAsync(deg, 0, N_NODES * sizeof(int), stream);
  // fp32 copies of x and weights
  k_convert_f<<<50000, 256, 0, stream>>>(x, H, (long)N_NODES * DIM, flag);
  k_convert_f<<<192, 256, 0, stream>>>(W1, W1f, 49152, flag);
  k_convert_f<<<192, 256, 0, stream>>>(W2, W2f, 49152, flag);
  k_convert_f<<<2, 256, 0, stream>>>(b1, b1f, 384, flag);
  k_convert_f<<<2, 256, 0, stream>>>(b2, b2f, 384, flag);
  k_cbn<<<NLAY * NRES * NCODE, 64, 0, stream>>>(cb, cbn, flag);
  k_gram<<<NLAY * 48 * 48, 64, 0, stream>>>(cbn, G);
  // CSR build (once; reused all 3 layers)
  k_hist<<<(N_EDGES + 255) / 256, 256, 0, stream>>>(ei, deg);
  k_scan1<<<SCAN_NB, 256, 0, stream>>>(deg, bsum);
  k_scan2<<<1, 512, 0, stream>>>(bsum);
  k_scan3<<<SCAN_NB, 256, 0, stream>>>(deg, bsum, ofs, cursor);
  k_fill<<<(N_EDGES + 255) / 256, 256, 0, stream>>>(ei, cursor, csr);

  for (int l = 0; l < NLAY; l++) {
    k_gather<<<N_NODES / 4, 256, 0, stream>>>(H, ofs, csr, T1);
    k_gemm_relu_f<<<GEMM_NB, 256, 0, stream>>>(T1, W1f + l * DIM * DIM, b1f + l * DIM, T2);
    hipMemsetAsync(stats8, 0, 2048 * sizeof(double), stream);
    k_gemm_relu_stats<<<GEMM_NB, 256, 0, stream>>>(T2, W2f + l * DIM * DIM, b2f + l * DIM, T1, stats8);
    k_post<<<GEMM_NB, 256, 0, stream>>>(T1, stats8, gamma, beta, batch, d_out, xpool, hh, l, flag);
    k_dotH<<<1563, 256, 0, stream>>>(T1, cbn + (long)l * 48 * DIM, dH);
    k_vq<<<391, 256, 0, stream>>>(dH, hh, G + l * 48 * 48, d_out, commit, l, flag);
    // T1 becomes the new h; old H becomes scratch
    float* t = H; H = T1; T1 = t;
  }
  k_out<<<769, 256, 0, stream>>>(xpool, commit, d_out, flag);
}

// Round 10
// 1526.852 us; speedup vs baseline: 1.5078x; 1.0459x over previous
//
#include <hip/hip_runtime.h>
#include <hip/hip_bf16.h>

#define N_NODES 100000
#define N_EDGES 1600000
#define DIM 128
#define NLAY 3
#define NRES 3
#define NCODE 16
#define NGRAPH 512
#define SCAN_NB ((N_NODES + 255) / 256)  // 391
#define GEMM_NB ((N_NODES + 63) / 64)    // 1563

using bf16 = __hip_bfloat16;

__device__ inline void atomAddD(double* p, double v) { unsafeAtomicAdd(p, v); }

// flag==1: external float-typed arrays are bf16; flag==0: they are fp32.
__device__ inline double ldx(const void* p, long i, int isbf) {
  if (isbf) return (double)__bfloat162float(((const bf16*)p)[i]);
  return (double)((const float*)p)[i];
}
__device__ inline void stout(void* p, long i, double v, int isbf) {
  if (isbf) ((bf16*)p)[i] = __float2bfloat16((float)v);
  else ((float*)p)[i] = (float)v;
}

// ---------- dtype detection: bf16 vs fp32 bit-pattern statistics ----------
__global__ void k_detect(const unsigned int* __restrict__ x, int* __restrict__ flag) {
  int tid = threadIdx.x;  // 256
  int cnt = 0;
  for (int j = tid; j < 1024; j += 256) {
    unsigned int u = x[j];
    int e = (u >> 7) & 0xFF;  // exponent field of the LOW u16 viewed as bf16
    cnt += (e >= 100 && e <= 135) ? 1 : 0;
  }
  __shared__ int sh[256];
  sh[tid] = cnt; __syncthreads();
  for (int s = 128; s; s >>= 1) { if (tid < s) sh[tid] += sh[tid + s]; __syncthreads(); }
  if (tid == 0) flag[0] = (sh[0] > 512) ? 1 : 0;
}

// ---------- external -> fp32 convert (weights only now) ----------
__global__ __launch_bounds__(256) void k_convert_f(const void* __restrict__ x, float* __restrict__ hf,
                                                   long n, const int* __restrict__ flag) {
  int isbf = flag[0];
  long i = (long)blockIdx.x * 256 + threadIdx.x;
  if (i < n) hf[i] = (float)ldx(x, i, isbf);
}

// ---------- CSR build: histogram ----------
__global__ __launch_bounds__(256) void k_hist(const int* __restrict__ ei, int* __restrict__ deg) {
  int e = blockIdx.x * 256 + threadIdx.x;
  if (e < N_EDGES) atomicAdd(&deg[ei[N_EDGES + e]], 1);
}

// ---------- CSR build: hierarchical exclusive scan (3 phases, all parallel) ----------
__global__ __launch_bounds__(256) void k_scan1(const int* __restrict__ deg, int* __restrict__ bsum) {
  int i = blockIdx.x * 256 + threadIdx.x;
  int v = (i < N_NODES) ? deg[i] : 0;
  for (int o = 32; o; o >>= 1) v += __shfl_xor(v, o);
  __shared__ int sh[4];
  if ((threadIdx.x & 63) == 0) sh[threadIdx.x >> 6] = v;
  __syncthreads();
  if (threadIdx.x == 0) bsum[blockIdx.x] = sh[0] + sh[1] + sh[2] + sh[3];
}

__global__ void k_scan2(int* __restrict__ bsum) {
  __shared__ int sh[512];
  int t = threadIdx.x;
  int v = (t < SCAN_NB) ? bsum[t] : 0;
  sh[t] = v; __syncthreads();
  for (int s = 1; s < 512; s <<= 1) {
    int add = (t >= s) ? sh[t - s] : 0;
    __syncthreads();
    sh[t] += add;
    __syncthreads();
  }
  if (t < SCAN_NB) bsum[t] = sh[t] - v;  // exclusive
}

__global__ __launch_bounds__(256) void k_scan3(const int* __restrict__ deg, const int* __restrict__ bsum,
                                               int* __restrict__ ofs, int* __restrict__ cursor) {
  int t = threadIdx.x;
  int i = blockIdx.x * 256 + t;
  int v = (i < N_NODES) ? deg[i] : 0;
  __shared__ int sh[256];
  sh[t] = v; __syncthreads();
  for (int s = 1; s < 256; s <<= 1) {
    int add = (t >= s) ? sh[t - s] : 0;
    __syncthreads();
    sh[t] += add;
    __syncthreads();
  }
  int excl = sh[t] - v + bsum[blockIdx.x];
  if (i < N_NODES) { ofs[i] = excl; cursor[i] = excl; }
  if (i == N_NODES - 1) ofs[N_NODES] = excl + v;
}

// ---------- CSR build: fill ----------
__global__ __launch_bounds__(256) void k_fill(const int* __restrict__ ei, int* __restrict__ cursor,
                                              int* __restrict__ csr) {
  int e = blockIdx.x * 256 + threadIdx.x;
  if (e < N_EDGES) {
    int d = ei[N_EDGES + e];
    int p = atomicAdd(&cursor[d], 1);
    csr[p] = ei[e];
  }
}

// ---------- gather (layers 1-2): out[n] = h[n] + sum h[src_j]  (VERBATIM R6 body) ----------
// blocks 0-7 additionally zero one stats8 slab each (written only by the NEXT kernel).
__global__ __launch_bounds__(256) void k_gather(const float* __restrict__ hf,
                                                const int* __restrict__ ofs,
                                                const int* __restrict__ csr,
                                                float* __restrict__ outQ,
                                                double* __restrict__ stats8) {
  if (blockIdx.x < 8) stats8[blockIdx.x * 256 + threadIdx.x] = 0.0;
  int node = blockIdx.x * 4 + (threadIdx.x >> 6);
  int lane = threadIdx.x & 63;
  int beg = ofs[node], end = ofs[node + 1];
  float2 sv = *(const float2*)&hf[(long)node * DIM + lane * 2];
  double accx = (double)sv.x, accy = (double)sv.y;
  int j = beg;
  for (; j + 3 < end; j += 4) {
    int s0 = csr[j], s1 = csr[j + 1], s2 = csr[j + 2], s3 = csr[j + 3];
    float2 v0 = *(const float2*)&hf[(long)s0 * DIM + lane * 2];
    float2 v1 = *(const float2*)&hf[(long)s1 * DIM + lane * 2];
    float2 v2 = *(const float2*)&hf[(long)s2 * DIM + lane * 2];
    float2 v3 = *(const float2*)&hf[(long)s3 * DIM + lane * 2];
    accx += (double)v0.x; accy += (double)v0.y;
    accx += (double)v1.x; accy += (double)v1.y;
    accx += (double)v2.x; accy += (double)v2.y;
    accx += (double)v3.x; accy += (double)v3.y;
  }
  for (; j < end; j++) {
    int s0 = csr[j];
    float2 v0 = *(const float2*)&hf[(long)s0 * DIM + lane * 2];
    accx += (double)v0.x; accy += (double)v0.y;
  }
  *(float2*)&outQ[(long)node * DIM + lane * 2] = make_float2((float)accx, (float)accy);
}

// ---------- gather (layer 0): source is the EXTERNAL x, converted inline ----------
// bf16->fp32 is exact bit placement (u<<16), so values and add order are bit-identical
// to the old convert-then-gather path; bytes halve when input is bf16.
__global__ __launch_bounds__(256) void k_gather_x(const void* __restrict__ x,
                                                  const int* __restrict__ ofs,
                                                  const int* __restrict__ csr,
                                                  float* __restrict__ outQ,
                                                  double* __restrict__ stats8,
                                                  const int* __restrict__ flag) {
  if (blockIdx.x < 8) stats8[blockIdx.x * 256 + threadIdx.x] = 0.0;
  int isbf = flag[0];
  int node = blockIdx.x * 4 + (threadIdx.x >> 6);
  int lane = threadIdx.x & 63;
  int beg = ofs[node], end = ofs[node + 1];
  double accx, accy;
  if (isbf) {
    const unsigned short* xb = (const unsigned short*)x;
    unsigned int u = *(const unsigned int*)&xb[(long)node * DIM + lane * 2];
    accx = (double)__uint_as_float(u << 16);
    accy = (double)__uint_as_float(u & 0xffff0000u);
    int j = beg;
    for (; j + 3 < end; j += 4) {
      int s0 = csr[j], s1 = csr[j + 1], s2 = csr[j + 2], s3 = csr[j + 3];
      unsigned int u0 = *(const unsigned int*)&xb[(long)s0 * DIM + lane * 2];
      unsigned int u1 = *(const unsigned int*)&xb[(long)s1 * DIM + lane * 2];
      unsigned int u2 = *(const unsigned int*)&xb[(long)s2 * DIM + lane * 2];
      unsigned int u3 = *(const unsigned int*)&xb[(long)s3 * DIM + lane * 2];
      accx += (double)__uint_as_float(u0 << 16); accy += (double)__uint_as_float(u0 & 0xffff0000u);
      accx += (double)__uint_as_float(u1 << 16); accy += (double)__uint_as_float(u1 & 0xffff0000u);
      accx += (double)__uint_as_float(u2 << 16); accy += (double)__uint_as_float(u2 & 0xffff0000u);
      accx += (double)__uint_as_float(u3 << 16); accy += (double)__uint_as_float(u3 & 0xffff0000u);
    }
    for (; j < end; j++) {
      int s0 = csr[j];
      unsigned int u0 = *(const unsigned int*)&xb[(long)s0 * DIM + lane * 2];
      accx += (double)__uint_as_float(u0 << 16); accy += (double)__uint_as_float(u0 & 0xffff0000u);
    }
  } else {
    const float* hf = (const float*)x;
    float2 sv = *(const float2*)&hf[(long)node * DIM + lane * 2];
    accx = (double)sv.x; accy = (double)sv.y;
    int j = beg;
    for (; j + 3 < end; j += 4) {
      int s0 = csr[j], s1 = csr[j + 1], s2 = csr[j + 2], s3 = csr[j + 3];
      float2 v0 = *(const float2*)&hf[(long)s0 * DIM + lane * 2];
      float2 v1 = *(const float2*)&hf[(long)s1 * DIM + lane * 2];
      float2 v2 = *(const float2*)&hf[(long)s2 * DIM + lane * 2];
      float2 v3 = *(const float2*)&hf[(long)s3 * DIM + lane * 2];
      accx += (double)v0.x; accy += (double)v0.y;
      accx += (double)v1.x; accy += (double)v1.y;
      accx += (double)v2.x; accy += (double)v2.y;
      accx += (double)v3.x; accy += (double)v3.y;
    }
    for (; j < end; j++) {
      int s0 = csr[j];
      float2 v0 = *(const float2*)&hf[(long)s0 * DIM + lane * 2];
      accx += (double)v0.x; accy += (double)v0.y;
    }
  }
  *(float2*)&outQ[(long)node * DIM + lane * 2] = make_float2((float)accx, (float)accy);
}

// ---------- normalize codebooks (fp64) ----------
__global__ void k_cbn(const void* __restrict__ cb, double* __restrict__ cbn, const int* __restrict__ flag) {
  int isbf = flag[0];
  int b = blockIdx.x, d = threadIdx.x;  // 144 blocks x 64 threads
  double v0 = ldx(cb, (long)b * DIM + d, isbf);
  double v1 = ldx(cb, (long)b * DIM + d + 64, isbf);
  double ss = v0 * v0 + v1 * v1;
  for (int o = 32; o; o >>= 1) ss += __shfl_xor(ss, o);
  double inv = 1.0 / sqrt(ss + 1e-12);
  cbn[b * DIM + d] = v0 * inv;
  cbn[b * DIM + d + 64] = v1 * inv;
}

// ---------- Gram matrices per layer ----------
__global__ void k_gram(const double* __restrict__ cbn, double* __restrict__ G) {
  int b = blockIdx.x, t = threadIdx.x;  // 3*48*48 blocks x 64
  int l = b / (48 * 48); int rem = b % (48 * 48); int a = rem / 48, c = rem % 48;
  const double* ra = cbn + (long)(l * 48 + a) * DIM;
  const double* rc = cbn + (long)(l * 48 + c) * DIM;
  double s = ra[t] * rc[t] + ra[t + 64] * rc[t + 64];
  for (int o = 32; o; o >>= 1) s += __shfl_xor(s, o);
  if (t == 0) G[b] = s;
}

// ---------- FUSED GEMM1 + GEMM2 + BN-stats: both inner loops VERBATIM R3 body ----------
// GEMM1 -> bias1+relu in-register (same expressions) -> tile back to LDS ->
// GEMM2 (verbatim) -> bias2+relu+store+fp64 stats epilogue (verbatim R9).
__global__ __launch_bounds__(256) void k_gemm_pair(const float* __restrict__ in,
                                                   const float* __restrict__ W1g,
                                                   const float* __restrict__ b1g,
                                                   const float* __restrict__ W2g,
                                                   const float* __restrict__ b2g,
                                                   float* __restrict__ out,
                                                   double* __restrict__ stats8) {
  __shared__ __align__(16) float ul[64 * DIM];  // 32 KB
  int tid = threadIdx.x;
  long base = (long)blockIdx.x * 64;
  for (int j = tid; j < 64 * DIM / 4; j += 256) {
    long row = base + (j >> 5);
    float4 v = make_float4(0.f, 0.f, 0.f, 0.f);
    if (row < N_NODES) v = *(const float4*)&in[base * DIM + (long)j * 4];
    *(float4*)&ul[j * 4] = v;
  }
  __syncthreads();
  int cl = tid & 31;
  int rw = tid >> 5;
  int c0 = cl * 4;
  float acc[8][4] = {};
  // ---- GEMM1 (verbatim) ----
  for (int k = 0; k < DIM; k += 4) {
    float4 w0 = *(const float4*)&W1g[(k + 0) * DIM + c0];
    float4 w1 = *(const float4*)&W1g[(k + 1) * DIM + c0];
    float4 w2 = *(const float4*)&W1g[(k + 2) * DIM + c0];
    float4 w3 = *(const float4*)&W1g[(k + 3) * DIM + c0];
#pragma unroll
    for (int r = 0; r < 8; r++) {
      float4 u = *(const float4*)&ul[(rw * 8 + r) * DIM + k];
      acc[r][0] += u.x * w0.x + u.y * w1.x + u.z * w2.x + u.w * w3.x;
      acc[r][1] += u.x * w0.y + u.y * w1.y + u.z * w2.y + u.w * w3.y;
      acc[r][2] += u.x * w0.z + u.y * w1.z + u.z * w2.z + u.w * w3.z;
      acc[r][3] += u.x * w0.w + u.y * w1.w + u.z * w2.w + u.w * w3.w;
    }
  }
  {
    float4 bv = *(const float4*)&b1g[c0];
#pragma unroll
    for (int r = 0; r < 8; r++) {
      acc[r][0] = fmaxf(acc[r][0] + bv.x, 0.f);
      acc[r][1] = fmaxf(acc[r][1] + bv.y, 0.f);
      acc[r][2] = fmaxf(acc[r][2] + bv.z, 0.f);
      acc[r][3] = fmaxf(acc[r][3] + bv.w, 0.f);
    }
  }
  __syncthreads();  // all GEMM1 LDS reads complete
#pragma unroll
  for (int r = 0; r < 8; r++)
    *(float4*)&ul[(rw * 8 + r) * DIM + c0] = make_float4(acc[r][0], acc[r][1], acc[r][2], acc[r][3]);
  __syncthreads();
#pragma unroll
  for (int r = 0; r < 8; r++) { acc[r][0] = 0.f; acc[r][1] = 0.f; acc[r][2] = 0.f; acc[r][3] = 0.f; }
  // ---- GEMM2 (verbatim) ----
  for (int k = 0; k < DIM; k += 4) {
    float4 w0 = *(const float4*)&W2g[(k + 0) * DIM + c0];
    float4 w1 = *(const float4*)&W2g[(k + 1) * DIM + c0];
    float4 w2 = *(const float4*)&W2g[(k + 2) * DIM + c0];
    float4 w3 = *(const float4*)&W2g[(k + 3) * DIM + c0];
#pragma unroll
    for (int r = 0; r < 8; r++) {
      float4 u = *(const float4*)&ul[(rw * 8 + r) * DIM + k];
      acc[r][0] += u.x * w0.x + u.y * w1.x + u.z * w2.x + u.w * w3.x;
      acc[r][1] += u.x * w0.y + u.y * w1.y + u.z * w2.y + u.w * w3.y;
      acc[r][2] += u.x * w0.z + u.y * w1.z + u.z * w2.z + u.w * w3.z;
      acc[r][3] += u.x * w0.w + u.y * w1.w + u.z * w2.w + u.w * w3.w;
    }
  }
  float4 bv = *(const float4*)&b2g[c0];
  double cs0 = 0.0, cs1 = 0.0, cs2 = 0.0, cs3 = 0.0;
  double q0 = 0.0, q1 = 0.0, q2 = 0.0, q3 = 0.0;
#pragma unroll
  for (int r = 0; r < 8; r++) {
    long row = base + rw * 8 + r;
    if (row < N_NODES) {
      float4 o;
      o.x = fmaxf(acc[r][0] + bv.x, 0.f);
      o.y = fmaxf(acc[r][1] + bv.y, 0.f);
      o.z = fmaxf(acc[r][2] + bv.z, 0.f);
      o.w = fmaxf(acc[r][3] + bv.w, 0.f);
      *(float4*)&out[row * DIM + c0] = o;
      double dx = (double)o.x, dy = (double)o.y, dz = (double)o.z, dw = (double)o.w;
      cs0 += dx; q0 += dx * dx;
      cs1 += dy; q1 += dy * dy;
      cs2 += dz; q2 += dz * dz;
      cs3 += dw; q3 += dw * dw;
    }
  }
  __syncthreads();  // ul reads complete; reuse as fp64 reduction space
  double* sred = (double*)ul;
  sred[rw * 128 + c0 + 0] = cs0; sred[1024 + rw * 128 + c0 + 0] = q0;
  sred[rw * 128 + c0 + 1] = cs1; sred[1024 + rw * 128 + c0 + 1] = q1;
  sred[rw * 128 + c0 + 2] = cs2; sred[1024 + rw * 128 + c0 + 2] = q2;
  sred[rw * 128 + c0 + 3] = cs3; sred[1024 + rw * 128 + c0 + 3] = q3;
  __syncthreads();
  if (tid < 128) {
    double S = 0.0, S2 = 0.0;
#pragma unroll
    for (int i = 0; i < 8; i++) { S += sred[i * 128 + tid]; S2 += sred[1024 + i * 128 + tid]; }
    int slab = blockIdx.x & 7;
    atomAddD(&stats8[slab * 256 + tid], S);
    atomAddD(&stats8[slab * 256 + 128 + tid], S2);
  }
}

// ---------- fused post: bn_prep(8-slab) + normalize + xs + hh + xpool (VERBATIM R9) ----------
__global__ __launch_bounds__(256) void k_post(float* __restrict__ h,
                                              const double* __restrict__ stats8,
                                              const void* __restrict__ gamma,
                                              const void* __restrict__ beta,
                                              const int* __restrict__ batch,
                                              void* __restrict__ out,
                                              double* __restrict__ xpool,
                                              double* __restrict__ hh,
                                              int l, const int* __restrict__ flag) {
  __shared__ float hl[64 * 132];   // normalized tile (fp32), padded
  __shared__ double hq[64 * 4];    // ||h||^2 quarter-partials
  __shared__ double ssl[256];      // BN scale/shift
  __shared__ int sbat[64];
  int isbf = flag[0];
  int tid = threadIdx.x;
  long base = (long)blockIdx.x * 64;
  if (tid < 128) {
    double sum = 0.0, sumsq = 0.0;
#pragma unroll
    for (int s8 = 0; s8 < 8; s8++) { sum += stats8[s8 * 256 + tid]; sumsq += stats8[s8 * 256 + 128 + tid]; }
    double mean = sum / (double)N_NODES;
    double var = sumsq / (double)N_NODES - mean * mean;
    double sc = ldx(gamma, (long)l * DIM + tid, isbf) / sqrt(var + 1e-5);
    ssl[tid] = sc;
    ssl[DIM + tid] = ldx(beta, (long)l * DIM + tid, isbf) - mean * sc;
  }
  if (tid < 64) {
    long row = base + tid;
    sbat[tid] = (row < N_NODES) ? batch[row] : -1;
  }
  __syncthreads();
  // phase 1: normalize (fp64 math) + write h + xs + stage tile
  int d = tid & 127, half = tid >> 7;
  double sc = ssl[d], sh = ssl[DIM + d];
  const long XS_BASE = (long)NGRAPH * DIM * NLAY;
  for (int rr = half; rr < 64; rr += 2) {
    long row = base + rr;
    float vf = 0.f;
    if (row < N_NODES) {
      double v = (double)h[row * DIM + d] * sc + sh;
      vf = (float)v;
      h[row * DIM + d] = vf;
      stout(out, XS_BASE + row * (DIM * NLAY) + l * DIM + d, v, isbf);
    }
    hl[rr * 132 + d] = vf;
  }
  __syncthreads();
  // phase 2: hh quarter-partials
  {
    int row = tid >> 2, q = tid & 3;
    double s2 = 0.0;
    const float* hp = &hl[row * 132 + q * 32];
#pragma unroll
    for (int i = 0; i < 32; i++) { double v = (double)hp[i]; s2 += v * v; }
    hq[row * 4 + q] = s2;
  }
  __syncthreads();
  // phase 3 (wave 0): hh write ; (waves 2-3): xpool segments
  if (tid < 64) {
    long n = base + tid;
    if (n < N_NODES) hh[n] = hq[tid * 4] + hq[tid * 4 + 1] + hq[tid * 4 + 2] + hq[tid * 4 + 3];
  } else if (tid >= 128) {
    int dd = tid - 128;
    int g = sbat[0];
    double acc = 0.0;
    for (int r = 0; r < 64; r++) {
      int gg = sbat[r];
      if (gg < 0) break;
      if (gg != g) {
        atomAddD(&xpool[(long)g * (DIM * NLAY) + l * DIM + dd], acc);
        acc = 0.0; g = gg;
      }
      acc += (double)hl[r * 132 + dd];
    }
    atomAddD(&xpool[(long)g * (DIM * NLAY) + l * DIM + dd], acc);
  }
}

// ---------- dotH = h @ cbn^T (48 cols), fp32 h, fp64 cbn LDS, fp64 accum, fp32 store ----------
// (VERBATIM Round-3 kernel — ID-path numerics proven against the harness reference)
__global__ __launch_bounds__(256) void k_dotH(const float* __restrict__ hn,
                                              const double* __restrict__ cbnL,
                                              float* __restrict__ dH) {
  __shared__ double cl[48 * 134];
  int tid = threadIdx.x;
  for (int j = tid; j < 48 * DIM; j += 256) { int c = j >> 7, k = j & 127; cl[c * 134 + k] = cbnL[j]; }
  __syncthreads();
  int ct = tid & 7; int c0 = ct * 6; int rt = tid >> 3;
  long r0 = (long)blockIdx.x * 64 + rt; long r1 = r0 + 32;
  long r0c = r0 < N_NODES ? r0 : (N_NODES - 1);
  long r1c = r1 < N_NODES ? r1 : (N_NODES - 1);
  double acc0[6] = {}, acc1[6] = {};
  for (int k = 0; k < DIM; k += 4) {
    float4 h0 = *(const float4*)&hn[r0c * DIM + k];
    float4 h1 = *(const float4*)&hn[r1c * DIM + k];
#pragma unroll
    for (int j = 0; j < 6; j++) {
      double2 ca = *(const double2*)&cl[(c0 + j) * 134 + k];
      double2 cb = *(const double2*)&cl[(c0 + j) * 134 + k + 2];
      acc0[j] += (double)h0.x * ca.x + (double)h0.y * ca.y + (double)h0.z * cb.x + (double)h0.w * cb.y;
      acc1[j] += (double)h1.x * ca.x + (double)h1.y * ca.y + (double)h1.z * cb.x + (double)h1.w * cb.y;
    }
  }
  if (r0 < N_NODES) {
#pragma unroll
    for (int j = 0; j < 6; j++) dH[r0 * 48 + c0 + j] = (float)acc0[j];
  }
  if (r1 < N_NODES) {
#pragma unroll
    for (int j = 0; j < 6; j++) dH[r1 * 48 + c0 + j] = (float)acc1[j];
  }
}

// ---------- VQ select via dotH & Gram; ids + commit (VERBATIM Round-3 kernel) ----------
__global__ __launch_bounds__(256) void k_vq(const float* __restrict__ dH, const double* __restrict__ hh,
                                            const double* __restrict__ G, void* __restrict__ out,
                                            double* __restrict__ commit, int l, const int* __restrict__ flag) {
  int isbf = flag[0];
  __shared__ double Gl[48 * 48];
  int tid = threadIdx.x;
  for (int j = tid; j < 48 * 48; j += 256) Gl[j] = G[j];
  __syncthreads();
  long n = (long)blockIdx.x * 256 + tid;
  double csum = 0.0;
  if (n < N_NODES) {
    double dh[48];
#pragma unroll
    for (int c = 0; c < 48; c++) dh[c] = (double)dH[n * 48 + c];
    int i0 = 0; double b0 = dh[0];
#pragma unroll
    for (int c = 1; c < 16; c++) { if (dh[c] > b0) { b0 = dh[c]; i0 = c; } }
    int i1 = 0; double b1 = dh[16] - Gl[i0 * 48 + 16];
#pragma unroll
    for (int c = 1; c < 16; c++) {
      double s = dh[16 + c] - Gl[i0 * 48 + 16 + c];
      if (s > b1) { b1 = s; i1 = c; }
    }
    int i2 = 0; double b2 = dh[32] - Gl[i0 * 48 + 32] - Gl[(16 + i1) * 48 + 32];
#pragma unroll
    for (int c = 1; c < 16; c++) {
      double s = dh[32 + c] - Gl[i0 * 48 + 32 + c] - Gl[(16 + i1) * 48 + 32 + c];
      if (s > b2) { b2 = s; i2 = c; }
    }
    double r1s = hh[n] - 2.0 * b0 + Gl[i0 * 48 + i0];
    double r2s = r1s - 2.0 * b1 + Gl[(16 + i1) * 48 + 16 + i1];
    double r3s = r2s - 2.0 * b2 + Gl[(32 + i2) * 48 + 32 + i2];
    csum = r1s + r2s + r3s;
    const long IDS_BASE = (long)NGRAPH * DIM * NLAY + (long)N_NODES * DIM * NLAY + 1;
    long base = IDS_BASE + n * (NLAY * NRES) + l * NRES;
    stout(out, base + 0, (double)i0, isbf);
    stout(out, base + 1, (double)i1, isbf);
    stout(out, base + 2, (double)i2, isbf);
  }
  for (int o = 32; o; o >>= 1) csum += __shfl_xor(csum, o);
  if ((tid & 63) == 0 && csum != 0.0) atomAddD(commit, csum);
}

// ---------- final: xpool + commit -> out ----------
__global__ __launch_bounds__(256) void k_out(const double* __restrict__ xpool, const double* __restrict__ commit,
                                             void* __restrict__ out, const int* __restrict__ flag) {
  int isbf = flag[0];
  long i = (long)blockIdx.x * 256 + threadIdx.x;
  const long NP = (long)NGRAPH * DIM * NLAY;
  if (i < NP) {
    stout(out, i, xpool[i], isbf);
  } else if (i == NP) {
    double c = commit[0] * (0.25 / ((double)N_NODES * (double)DIM));
    stout(out, NP + (long)N_NODES * DIM * NLAY, c, isbf);
  }
}

extern "C" void kernel_launch(void* const* d_in, const int* in_sizes, int n_in,
                              void* d_out, int out_size, void* d_ws, size_t ws_size,
                              hipStream_t stream) {
  const void* x = d_in[0];
  const int* ei = (const int*)d_in[1];
  const int* batch = (const int*)d_in[2];
  const void* W1 = d_in[3];
  const void* b1 = d_in[4];
  const void* W2 = d_in[5];
  const void* b2 = d_in[6];
  const void* gamma = d_in[7];
  const void* beta = d_in[8];
  const void* cb = d_in[9];

  double* w = (double*)d_ws;
  double* cbn = w;                      // 18,432
  double* G = cbn + 18432;              // 6,912
  double* stats8 = G + 6912;            // 2,048 (8 slabs x 256)
  double* hh = stats8 + 2048;           // 100,000
  double* xpool = hh + N_NODES;         // 196,608
  double* commit = xpool + (long)NGRAPH * DIM * NLAY;  // 1 (+1 pad)
  float* W1f = (float*)(commit + 2);    // 49,152
  float* W2f = W1f + 49152;             // 49,152
  float* b1f = W2f + 49152;             // 384
  float* b2f = b1f + 384;               // 384
  float* buf0 = b2f + 384;              // 12,800,000 (gather output)
  float* buf1 = buf0 + 12800000;        // 12,800,000 (h ping)
  float* buf2 = buf1 + 12800000;        // 12,800,000 (h pong)
  float* dH = buf2 + 12800000;          // 4,800,000
  int* ibuf = (int*)(dH + 4800000);
  int* flag = ibuf;                     // 1 (+pad)
  int* deg = ibuf + 64;                 // N_NODES
  int* ofs = deg + N_NODES;             // N_NODES + 1
  int* cursor = ofs + N_NODES + 1;      // N_NODES
  int* csr = cursor + N_NODES;          // N_EDGES
  int* bsum = csr + N_EDGES;            // SCAN_NB (391)

  k_detect<<<1, 256, 0, stream>>>((const unsigned int*)x, flag);
  // zero accumulators (xpool + commit contiguous)
  hipMemsetAsync(xpool, 0, ((long)NGRAPH * DIM * NLAY + 1) * sizeof(double), stream);
  hipMemsetAsync(deg, 0, N_NODES * sizeof(int), stream);
  // fp32 copies of weights only (layer-0 gather reads x directly now)
  k_convert_f<<<192, 256, 0, stream>>>(W1, W1f, 49152, flag);
  k_convert_f<<<192, 256, 0, stream>>>(W2, W2f, 49152, flag);
  k_convert_f<<<2, 256, 0, stream>>>(b1, b1f, 384, flag);
  k_convert_f<<<2, 256, 0, stream>>>(b2, b2f, 384, flag);
  k_cbn<<<NLAY * NRES * NCODE, 64, 0, stream>>>(cb, cbn, flag);
  k_gram<<<NLAY * 48 * 48, 64, 0, stream>>>(cbn, G);
  // CSR build (once; reused all 3 layers)
  k_hist<<<(N_EDGES + 255) / 256, 256, 0, stream>>>(ei, deg);
  k_scan1<<<SCAN_NB, 256, 0, stream>>>(deg, bsum);
  k_scan2<<<1, 512, 0, stream>>>(bsum);
  k_scan3<<<SCAN_NB, 256, 0, stream>>>(deg, bsum, ofs, cursor);
  k_fill<<<(N_EDGES + 255) / 256, 256, 0, stream>>>(ei, cursor, csr);

  float* Hcur = nullptr;  // current h (fp32); layer 0 sources from x directly
  for (int l = 0; l < NLAY; l++) {
    float* PO = (l & 1) ? buf2 : buf1;  // pair output / new h (always != Hcur)
    if (l == 0)
      k_gather_x<<<N_NODES / 4, 256, 0, stream>>>(x, ofs, csr, buf0, stats8, flag);
    else
      k_gather<<<N_NODES / 4, 256, 0, stream>>>(Hcur, ofs, csr, buf0, stats8);
    k_gemm_pair<<<GEMM_NB, 256, 0, stream>>>(buf0, W1f + l * DIM * DIM, b1f + l * DIM,
                                             W2f + l * DIM * DIM, b2f + l * DIM, PO, stats8);
    k_post<<<GEMM_NB, 256, 0, stream>>>(PO, stats8, gamma, beta, batch, d_out, xpool, hh, l, flag);
    k_dotH<<<1563, 256, 0, stream>>>(PO, cbn + (long)l * 48 * DIM, dH);
    k_vq<<<391, 256, 0, stream>>>(dH, hh, G + l * 48 * 48, d_out, commit, l, flag);
    Hcur = PO;
  }
  k_out<<<769, 256, 0, stream>>>(xpool, commit, d_out, flag);
}